// Round 7
// baseline (1528.613 us; speedup 1.0000x reference)
//
#include <hip/hip_runtime.h>
#include <hip/hip_bf16.h>

typedef __hip_bfloat16 bf16;
typedef __attribute__((ext_vector_type(8))) __bf16 bf16x8;
typedef __attribute__((ext_vector_type(4))) float f32x4;
typedef __attribute__((ext_vector_type(16))) float f32x16;
typedef __attribute__((ext_vector_type(4))) unsigned short us4;
typedef __attribute__((ext_vector_type(8))) unsigned short us8;

__device__ inline unsigned short f2bf(float f) {
    __hip_bfloat16 h = __float2bfloat16(f);
    return __builtin_bit_cast(unsigned short, h);
}
__device__ inline float bf2f(unsigned short u) {
    unsigned int x = ((unsigned int)u) << 16;
    return __builtin_bit_cast(float, x);
}

// async global->LDS 16B copy; LDS dst must be wave-uniform base + lane*16
typedef __attribute__((address_space(3))) unsigned int lds_uint;
typedef __attribute__((address_space(1))) const unsigned int g_uint;
__device__ inline void gload_lds16(const void* g, void* l) {
    __builtin_amdgcn_global_load_lds((g_uint*)g, (lds_uint*)l, 16, 0, 0);
}

__device__ inline void block_reduce_atomic(float v, float* dst) {
    #pragma unroll
    for (int o = 32; o > 0; o >>= 1) v += __shfl_down(v, o, 64);
    __shared__ float ws[8];
    const int lane = threadIdx.x & 63;
    const int wid  = threadIdx.x >> 6;
    if (lane == 0) ws[wid] = v;
    __syncthreads();
    if (threadIdx.x == 0) {
        float s = 0.f;
        const int nw = (blockDim.x + 63) >> 6;
        for (int i = 0; i < nw; ++i) s += ws[i];
        atomicAdd(dst, s);
    }
}

// ---------------------------------------------------------------------------
// small kernels
// ---------------------------------------------------------------------------
__global__ void zero_accs_kernel(float* accs, float* zbuf) {
    if (threadIdx.x < 8)  accs[threadIdx.x] = 0.f;
    if (threadIdx.x < 64) zbuf[threadIdx.x] = 0.f;
}

__global__ void mse_kernel(const float* __restrict__ a, const float* __restrict__ b,
                           float* __restrict__ acc, int n) {
    float s = 0.f;
    for (int i = blockIdx.x * blockDim.x + threadIdx.x; i < n; i += gridDim.x * blockDim.x) {
        float d = a[i] - b[i];
        s += d * d;
    }
    block_reduce_atomic(s, acc);
}

__global__ void ssim_kernel(const float* __restrict__ x, const float* __restrict__ y,
                            float* __restrict__ acc) {
    const int b = blockIdx.y;
    const int t = blockIdx.x * blockDim.x + threadIdx.x;
    float S = 0.f;
    if (t < 250 * 250) {
        const int i = t / 250, j = t - (t / 250) * 250;
        const float* xp = x + (size_t)b * 65536;
        const float* yp = y + (size_t)b * 65536;
        float sx = 0.f, sy = 0.f, sxx = 0.f, syy = 0.f, sxy = 0.f;
        #pragma unroll
        for (int dy = 0; dy < 7; ++dy) {
            const float* xr = xp + (size_t)(i + dy) * 256 + j;
            const float* yr = yp + (size_t)(i + dy) * 256 + j;
            #pragma unroll
            for (int dx = 0; dx < 7; ++dx) {
                float a = xr[dx], c = yr[dx];
                sx += a; sy += c;
                sxx += a * a; syy += c * c; sxy += a * c;
            }
        }
        const float inv = 1.f / 49.f;
        const float cn  = 49.f / 48.f;
        float ux = sx * inv, uy = sy * inv;
        float vx  = cn * (sxx * inv - ux * ux);
        float vy  = cn * (syy * inv - uy * uy);
        float vxy = cn * (sxy * inv - ux * uy);
        const float C1 = 1e-4f, C2 = 9e-4f;
        S = ((2.f * ux * uy + C1) * (2.f * vxy + C2)) /
            ((ux * ux + uy * uy + C1) * (vx + vy + C2));
    }
    block_reduce_atomic(S, acc);
}

__global__ void finalize_kernel(const float* __restrict__ accs, float* __restrict__ out) {
    if (threadIdx.x == 0) {
        float mse    = accs[0] * (1.f / 524288.f);
        float ssim_l = 1.f - accs[1] * (1.f / 500000.f);
        float perc   = accs[2] * (1.f / 33554432.f);
        out[0] = mse + 0.5f * ssim_l + 0.1f * perc;
        out[1] = mse;
        out[2] = ssim_l;
        out[3] = perc;
    }
}

// repack weights (CO,CIN,3,3) fp32 -> (CO, 9, CIN) bf16
__global__ void wprep_kernel(const float* __restrict__ w, bf16* __restrict__ wb,
                             int CIN, int CO) {
    int idx = blockIdx.x * blockDim.x + threadIdx.x;
    int n = CO * 9 * CIN;
    if (idx >= n) return;
    int ci = idx % CIN;
    int t  = (idx / CIN) % 9;
    int co = idx / (9 * CIN);
    wb[idx] = __float2bfloat16(w[((size_t)co * CIN + ci) * 9 + t]);
}

// ---------------------------------------------------------------------------
// conv1: CIN=1, CO=64, fp32 NCHW in -> bf16 NHWC out, relu
// ---------------------------------------------------------------------------
__global__ __launch_bounds__(256) void conv1_kernel(
    const float* __restrict__ in0, const float* __restrict__ w,
    const float* __restrict__ bias, bf16* __restrict__ out) {
    const int H = 256, W = 256;
    const int img = blockIdx.y;
    const float* in = in0 + (size_t)img * 65536;
    int px = blockIdx.x * 256 + threadIdx.x;
    int y = px >> 8, x = px & 255;
    float p[9];
    #pragma unroll
    for (int dy = 0; dy < 3; ++dy)
        #pragma unroll
        for (int dx = 0; dx < 3; ++dx) {
            int gy = y + dy - 1, gx = x + dx - 1;
            float v = 0.f;
            if ((unsigned)gy < (unsigned)H && (unsigned)gx < (unsigned)W)
                v = in[(size_t)gy * W + gx];
            p[dy * 3 + dx] = v;
        }
    bf16* op = out + ((size_t)img * H * W + px) * 64;
    #pragma unroll
    for (int c8 = 0; c8 < 8; ++c8) {
        us8 o;
        #pragma unroll
        for (int c = 0; c < 8; ++c) {
            int co = c8 * 8 + c;
            float a = bias[co];
            #pragma unroll
            for (int k = 0; k < 9; ++k) a += w[co * 9 + k] * p[k];
            o[c] = f2bf(fmaxf(a, 0.f));
        }
        *(us8*)(op + c8 * 8) = o;
    }
}

// ---------------------------------------------------------------------------
// implicit-GEMM 3x3 SAME conv, NHWC bf16 -> NHWC bf16, 32x32x16 MFMA.
// Block: 8 waves (512 thr), tile = 64 co x (32y x 16x). Wave wn: 4-row strip,
// m2n2 = 64 co x 64 px (acc 64 VGPR -> 4 waves/SIMD via launch_bounds(512,4)).
// WEIGHTS: direct global->VGPR (L2-hot, rolling 3-tap window, no LDS traffic,
// no cross-wave duplicate LDS reads).
// ACTIVATIONS: LDS, double-buffered 16-ch phases via global_load_lds:
//   buffer = [kh][34y][18x] x 16B = 19584 B; two buffers = 39168 B.
// K-loop: sync(p) -> issue act loads(p+1 -> other buf) -> compute(p);
// the barrier's vmcnt drain hits loads issued one full compute-phase ago.
// EPI: 0 = bias+relu store, 1 = +fused 2x2 maxpool, 2 = bias+relu then
// fused perceptual sum((x - fref)^2) accumulation (no store).
// ---------------------------------------------------------------------------
#define ABUF_CH 1224                 // chunks per buffer (2 kh * 34 * 18)
#define ABUF_SZ (ABUF_CH * 16)       // 19584 B

template <int CIN, int EPI>
__global__ __launch_bounds__(512, 4) void conv_wg512(
    const bf16* __restrict__ in,     // (NIMG, H, W, CIN)
    const bf16* __restrict__ wb,     // (CO, 9, CIN)
    const float* __restrict__ bias,  // (CO)
    bf16* __restrict__ out,          // NHWC (pooled dims if EPI==1)
    int H, int W, int CO,
    const float* __restrict__ zbuf,  // 64B zeroed scratch
    const bf16* __restrict__ fref,   // EPI==2: reference features
    float* __restrict__ pacc) {      // EPI==2: perceptual accumulator
    const int tid  = threadIdx.x;
    const int lane = tid & 63;
    const int wn   = tid >> 6;           // 0..7, 4-row y strip
    const int xl = lane & 15;
    const int yy = (lane >> 4) & 1;
    const int kh = lane >> 5;
    const int x0 = blockIdx.x * 16;
    const int y0 = blockIdx.y * 32;
    const int ngrp = CO >> 6;
    const int img = blockIdx.z / ngrp;
    const int co0 = (blockIdx.z - img * ngrp) << 6;

    __shared__ __align__(16) char smem[2 * ABUF_SZ];

    f32x16 acc[2][2];
    #pragma unroll
    for (int m = 0; m < 2; ++m)
        #pragma unroll
        for (int n = 0; n < 2; ++n)
            #pragma unroll
            for (int r = 0; r < 16; ++r) acc[m][n][r] = 0.f;

    const bf16* inp = in + (size_t)img * H * W * CIN;

    // ---- act staging sources (chunk c = tid + i*512, 3 slots) ----
    const char* srcp[3];
    unsigned live = 0;
    #pragma unroll
    for (int i = 0; i < 3; ++i) {
        int c = tid + i * 512;
        srcp[i] = (const char*)zbuf;
        if (c < ABUF_CH) {
            int khc = c / 612, p = c - khc * 612;
            int py = p / 18, px = p - py * 18;
            int gy = y0 - 1 + py, gx = x0 - 1 + px;
            if ((unsigned)gy < (unsigned)H && (unsigned)gx < (unsigned)W) {
                srcp[i] = (const char*)(inp + ((size_t)gy * W + gx) * CIN + khc * 8);
                live |= 1u << i;
            }
        }
    }
    const bool sl2 = (tid + 1024) < ABUF_CH;   // slot 2 partial

    // weight base (tap-centered at t=4); same for all waves, L2-hot
    const bf16* aw = wb + ((size_t)(co0 + (lane & 31)) * 9 + 4) * CIN + kh * 8;

    const char* bact0 = smem + (kh * 612 + (wn * 4 + yy) * 18 + xl) * 16;

    const int P = CIN / 16;

    // prologue: stage phase 0 into buffer 0
    {
        char* d = smem + tid * 16;
        gload_lds16(srcp[0], d);
        if (live & 1u) srcp[0] += 32;
        gload_lds16(srcp[1], d + 8192);
        if (live & 2u) srcp[1] += 32;
        if (sl2) {
            gload_lds16(srcp[2], d + 16384);
            if (live & 4u) srcp[2] += 32;
        }
    }

    for (int p = 0; p < P; ++p) {
        __syncthreads();   // drains own loads (issued one compute-phase ago)

        if (p + 1 < P) {   // issue next act phase into the other buffer
            char* d = smem + ((p + 1) & 1) * ABUF_SZ + tid * 16;
            gload_lds16(srcp[0], d);
            if (live & 1u) srcp[0] += 32;
            gload_lds16(srcp[1], d + 8192);
            if (live & 2u) srcp[1] += 32;
            if (sl2) {
                gload_lds16(srcp[2], d + 16384);
                if (live & 4u) srcp[2] += 32;
            }
        }

        const char* bact = bact0 + (p & 1) * ABUF_SZ;
        const bf16* awp = aw + p * 16;

        bf16x8 A[9][2];   // rolling window: only ~3 taps live at a time
        #pragma unroll
        for (int t = 0; t < 9; ++t) {
            if (t == 0) {
                #pragma unroll
                for (int tt = 0; tt < 2; ++tt) {
                    A[tt][0] = *(const bf16x8*)(awp + (tt - 4) * CIN);
                    A[tt][1] = *(const bf16x8*)(awp + (32 * 9 + tt - 4) * CIN);
                }
            }
            if (t + 2 < 9) {
                A[t + 2][0] = *(const bf16x8*)(awp + (t - 2) * CIN);
                A[t + 2][1] = *(const bf16x8*)(awp + (32 * 9 + t - 2) * CIN);
            }
            const int dy = t / 3, dx = t - dy * 3;
            bf16x8 B0 = *(const bf16x8*)(bact + ((0 + dy) * 18 + dx) * 16);
            bf16x8 B1 = *(const bf16x8*)(bact + ((2 + dy) * 18 + dx) * 16);
            acc[0][0] = __builtin_amdgcn_mfma_f32_32x32x16_bf16(A[t][0], B0, acc[0][0], 0, 0, 0);
            acc[1][0] = __builtin_amdgcn_mfma_f32_32x32x16_bf16(A[t][1], B0, acc[1][0], 0, 0, 0);
            acc[0][1] = __builtin_amdgcn_mfma_f32_32x32x16_bf16(A[t][0], B1, acc[0][1], 0, 0, 0);
            acc[1][1] = __builtin_amdgcn_mfma_f32_32x32x16_bf16(A[t][1], B1, acc[1][1], 0, 0, 0);
        }
    }

    // ---- epilogue ----
    // C/D (verified): col(pixel) = lane&31 -> (yy, xl); row(co within 32) =
    // (reg&3) + 8*(reg>>2) + 4*kh.
    if (EPI == 0) {
        #pragma unroll
        for (int m = 0; m < 2; ++m)
            #pragma unroll
            for (int nt = 0; nt < 2; ++nt) {
                const int y = y0 + wn * 4 + nt * 2 + yy;
                bf16* op = out + (((size_t)img * H + y) * W + (x0 + xl)) * CO;
                #pragma unroll
                for (int g = 0; g < 4; ++g) {
                    const int co = co0 + m * 32 + g * 8 + kh * 4;
                    const f32x4 bv = *(const f32x4*)(bias + co);
                    us4 o;
                    #pragma unroll
                    for (int r = 0; r < 4; ++r)
                        o[r] = f2bf(fmaxf(acc[m][nt][g * 4 + r] + bv[r], 0.f));
                    *(us4*)(op + co) = o;
                }
            }
    } else if (EPI == 1) {
        const int Hp = H >> 1, Wp = W >> 1;
        #pragma unroll
        for (int m = 0; m < 2; ++m)
            #pragma unroll
            for (int nt = 0; nt < 2; ++nt) {
                #pragma unroll
                for (int g = 0; g < 4; ++g) {
                    const int co = co0 + m * 32 + g * 8 + kh * 4;
                    const f32x4 bv = *(const f32x4*)(bias + co);
                    float vv[4];
                    #pragma unroll
                    for (int r = 0; r < 4; ++r) {
                        float v = fmaxf(acc[m][nt][g * 4 + r] + bv[r], 0.f);
                        float t1 = fmaxf(v, __shfl_xor(v, 16));   // fold yy
                        vv[r] = fmaxf(t1, __shfl_xor(t1, 1));     // fold x pair
                    }
                    if ((lane & 0x11) == 0) {
                        const int py = (y0 >> 1) + wn * 2 + nt;
                        const int px = (x0 >> 1) + (xl >> 1);
                        us4 o;
                        #pragma unroll
                        for (int r = 0; r < 4; ++r) o[r] = f2bf(vv[r]);
                        *(us4*)(out + (((size_t)img * Hp + py) * Wp + px) * CO + co) = o;
                    }
                }
            }
    } else {
        float s = 0.f;
        #pragma unroll
        for (int m = 0; m < 2; ++m)
            #pragma unroll
            for (int nt = 0; nt < 2; ++nt) {
                const int y = y0 + wn * 4 + nt * 2 + yy;
                const bf16* fp = fref + (((size_t)img * H + y) * W + (x0 + xl)) * CO;
                #pragma unroll
                for (int g = 0; g < 4; ++g) {
                    const int co = co0 + m * 32 + g * 8 + kh * 4;
                    const f32x4 bv = *(const f32x4*)(bias + co);
                    us4 f = *(const us4*)(fp + co);
                    #pragma unroll
                    for (int r = 0; r < 4; ++r) {
                        float v = fmaxf(acc[m][nt][g * 4 + r] + bv[r], 0.f);
                        float d = bf2f(f2bf(v)) - bf2f(f[r]);
                        s += d * d;
                    }
                }
            }
        // block reduce reusing smem
        #pragma unroll
        for (int o = 32; o > 0; o >>= 1) s += __shfl_down(s, o, 64);
        __syncthreads();
        if (lane == 0) *(float*)(smem + wn * 4) = s;
        __syncthreads();
        if (tid == 0) {
            float tot = 0.f;
            #pragma unroll
            for (int i = 0; i < 8; ++i) tot += *(float*)(smem + i * 4);
            atomicAdd(pacc, tot);
        }
    }
}

// ---------------------------------------------------------------------------
// launch
// ---------------------------------------------------------------------------
extern "C" void kernel_launch(void* const* d_in, const int* in_sizes, int n_in,
                              void* d_out, int out_size, void* d_ws, size_t ws_size,
                              hipStream_t stream) {
    const float* sr = (const float*)d_in[0];
    const float* hr = (const float*)d_in[1];
    const float* w1 = (const float*)d_in[2];
    const float* b1 = (const float*)d_in[3];
    const float* w2 = (const float*)d_in[4];
    const float* b2 = (const float*)d_in[5];
    const float* w3 = (const float*)d_in[6];
    const float* b3 = (const float*)d_in[7];
    const float* w4 = (const float*)d_in[8];
    const float* b4 = (const float*)d_in[9];
    float* out = (float*)d_out;

    char* ws = (char*)d_ws;
    size_t off = 0;
    float* accs = (float*)(ws + off); off += 256;
    float* zbuf = (float*)(ws + off); off += 256;
    bf16* wb2 = (bf16*)(ws + off); off += (size_t)128 * 9 * 64 * 2;
    bf16* wb3 = (bf16*)(ws + off); off += (size_t)256 * 9 * 128 * 2;
    bf16* wb4 = (bf16*)(ws + off); off += (size_t)256 * 9 * 256 * 2;
    const size_t fixed = (off + 255) & ~(size_t)255;

    const size_t MB = 1024u * 1024u;
    // per image: A/G 8MB, P 4MB, F 8MB = 20MB (sr/hr passes reuse A,P)
    int nb = 8;
    while (nb > 1 && fixed + (size_t)nb * 20 * MB > ws_size) nb >>= 1;

    bf16* A = (bf16*)(ws + fixed);                            // (nb,256,256,64)|(nb,128,128,256)
    bf16* P = (bf16*)(ws + fixed + (size_t)nb * 8 * MB);      // (nb,128,128,128)
    bf16* F = (bf16*)(ws + fixed + (size_t)nb * 12 * MB);     // (nb,128,128,256)

    zero_accs_kernel<<<1, 64, 0, stream>>>(accs, zbuf);
    wprep_kernel<<<288, 256, 0, stream>>>(w2, wb2, 64, 128);
    wprep_kernel<<<1152, 256, 0, stream>>>(w3, wb3, 128, 256);
    wprep_kernel<<<2304, 256, 0, stream>>>(w4, wb4, 256, 256);
    mse_kernel<<<2048, 256, 0, stream>>>(sr, hr, accs + 0, 524288);
    ssim_kernel<<<dim3(245, 8), 256, 0, stream>>>(sr, hr, accs + 1);

    for (int b0 = 0; b0 < 8; b0 += nb) {
        // ---- sr pass: features -> F ----
        conv1_kernel<<<dim3(256, nb), 256, 0, stream>>>(sr + (size_t)b0 * 65536, w1, b1, A);
        conv_wg512<64, 1><<<dim3(16, 8, nb * 2), 512, 0, stream>>>(
            A, wb2, b2, P, 256, 256, 128, zbuf, nullptr, nullptr);
        conv_wg512<128, 0><<<dim3(8, 4, nb * 4), 512, 0, stream>>>(
            P, wb3, b3, A, 128, 128, 256, zbuf, nullptr, nullptr);
        conv_wg512<256, 0><<<dim3(8, 4, nb * 4), 512, 0, stream>>>(
            A, wb4, b4, F, 128, 128, 256, zbuf, nullptr, nullptr);
        // ---- hr pass: features, fused perceptual vs F ----
        conv1_kernel<<<dim3(256, nb), 256, 0, stream>>>(hr + (size_t)b0 * 65536, w1, b1, A);
        conv_wg512<64, 1><<<dim3(16, 8, nb * 2), 512, 0, stream>>>(
            A, wb2, b2, P, 256, 256, 128, zbuf, nullptr, nullptr);
        conv_wg512<128, 0><<<dim3(8, 4, nb * 4), 512, 0, stream>>>(
            P, wb3, b3, A, 128, 128, 256, zbuf, nullptr, nullptr);
        conv_wg512<256, 2><<<dim3(8, 4, nb * 4), 512, 0, stream>>>(
            A, wb4, b4, nullptr, 128, 128, 256, zbuf, F, accs + 2);
    }

    finalize_kernel<<<1, 1, 0, stream>>>(accs, out);
}

// Round 8
// 710.987 us; speedup vs baseline: 2.1500x; 2.1500x over previous
//
#include <hip/hip_runtime.h>
#include <hip/hip_bf16.h>

typedef __hip_bfloat16 bf16;
typedef unsigned char u8;
typedef __attribute__((ext_vector_type(4))) float f32x4;
typedef __attribute__((ext_vector_type(4))) unsigned short us4;
typedef __attribute__((ext_vector_type(8))) unsigned short us8;

__device__ inline unsigned short f2bf(float f) {
    __hip_bfloat16 h = __float2bfloat16(f);
    return __builtin_bit_cast(unsigned short, h);
}
__device__ inline float bf2f(unsigned short u) {
    unsigned int x = ((unsigned int)u) << 16;
    return __builtin_bit_cast(float, x);
}

// async global->LDS 16B copy; LDS dst must be wave-uniform base + lane*16
typedef __attribute__((address_space(3))) unsigned int lds_uint;
typedef __attribute__((address_space(1))) const unsigned int g_uint;
__device__ inline void gload_lds16(const void* g, void* l) {
    __builtin_amdgcn_global_load_lds((g_uint*)g, (lds_uint*)l, 16, 0, 0);
}

__device__ inline void block_reduce_atomic(float v, float* dst) {
    #pragma unroll
    for (int o = 32; o > 0; o >>= 1) v += __shfl_down(v, o, 64);
    __shared__ float ws[8];
    const int lane = threadIdx.x & 63;
    const int wid  = threadIdx.x >> 6;
    if (lane == 0) ws[wid] = v;
    __syncthreads();
    if (threadIdx.x == 0) {
        float s = 0.f;
        const int nw = (blockDim.x + 63) >> 6;
        for (int i = 0; i < nw; ++i) s += ws[i];
        atomicAdd(dst, s);
    }
}

// ---------------------------------------------------------------------------
// small kernels
// ---------------------------------------------------------------------------
__global__ void zero_accs_kernel(float* accs, float* zbuf) {
    if (threadIdx.x < 8)  accs[threadIdx.x] = 0.f;
    if (threadIdx.x < 64) zbuf[threadIdx.x] = 0.f;
}

__global__ void mse_kernel(const float* __restrict__ a, const float* __restrict__ b,
                           float* __restrict__ acc, int n) {
    float s = 0.f;
    for (int i = blockIdx.x * blockDim.x + threadIdx.x; i < n; i += gridDim.x * blockDim.x) {
        float d = a[i] - b[i];
        s += d * d;
    }
    block_reduce_atomic(s, acc);
}

__global__ void ssim_kernel(const float* __restrict__ x, const float* __restrict__ y,
                            float* __restrict__ acc) {
    const int b = blockIdx.y;
    const int t = blockIdx.x * blockDim.x + threadIdx.x;
    float S = 0.f;
    if (t < 250 * 250) {
        const int i = t / 250, j = t - (t / 250) * 250;
        const float* xp = x + (size_t)b * 65536;
        const float* yp = y + (size_t)b * 65536;
        float sx = 0.f, sy = 0.f, sxx = 0.f, syy = 0.f, sxy = 0.f;
        #pragma unroll
        for (int dy = 0; dy < 7; ++dy) {
            const float* xr = xp + (size_t)(i + dy) * 256 + j;
            const float* yr = yp + (size_t)(i + dy) * 256 + j;
            #pragma unroll
            for (int dx = 0; dx < 7; ++dx) {
                float a = xr[dx], c = yr[dx];
                sx += a; sy += c;
                sxx += a * a; syy += c * c; sxy += a * c;
            }
        }
        const float inv = 1.f / 49.f;
        const float cn  = 49.f / 48.f;
        float ux = sx * inv, uy = sy * inv;
        float vx  = cn * (sxx * inv - ux * ux);
        float vy  = cn * (syy * inv - uy * uy);
        float vxy = cn * (sxy * inv - ux * uy);
        const float C1 = 1e-4f, C2 = 9e-4f;
        S = ((2.f * ux * uy + C1) * (2.f * vxy + C2)) /
            ((ux * ux + uy * uy + C1) * (vx + vy + C2));
    }
    block_reduce_atomic(S, acc);
}

__global__ void finalize_kernel(const float* __restrict__ accs, float* __restrict__ out) {
    if (threadIdx.x == 0) {
        float mse    = accs[0] * (1.f / 524288.f);
        float ssim_l = 1.f - accs[1] * (1.f / 500000.f);
        float perc   = accs[2] * (1.f / 33554432.f);
        out[0] = mse + 0.5f * ssim_l + 0.1f * perc;
        out[1] = mse;
        out[2] = ssim_l;
        out[3] = perc;
    }
}

// repack weights (CO,CIN,3,3) fp32 -> (CO, 9, CIN) fp8 e4m3
__global__ void wprep_fp8_kernel(const float* __restrict__ w, u8* __restrict__ wb,
                                 int CIN, int CO) {
    int idx = blockIdx.x * blockDim.x + threadIdx.x;   // one fp8 PAIR
    int n2 = CO * 9 * CIN / 2;
    if (idx >= n2) return;
    int e = idx * 2;
    int co = e / (9 * CIN);
    int rem = e - co * 9 * CIN;
    int t = rem / CIN;
    int ci = rem - t * CIN;                            // even
    float v0 = w[((size_t)co * CIN + ci) * 9 + t];
    float v1 = w[((size_t)co * CIN + ci + 1) * 9 + t];
    int r = __builtin_amdgcn_cvt_pk_fp8_f32(v0, v1, 0, false);
    *(unsigned short*)(wb + e) = (unsigned short)(r & 0xffff);
}

// ---------------------------------------------------------------------------
// conv1: CIN=1, CO=64, fp32 NCHW in -> fp8 NHWC out, relu
// ---------------------------------------------------------------------------
__global__ __launch_bounds__(256) void conv1_kernel(
    const float* __restrict__ in0, const float* __restrict__ w,
    const float* __restrict__ bias, u8* __restrict__ out) {
    const int H = 256, W = 256;
    const int img = blockIdx.y;
    const float* in = in0 + (size_t)img * 65536;
    int px = blockIdx.x * 256 + threadIdx.x;
    int y = px >> 8, x = px & 255;
    float p[9];
    #pragma unroll
    for (int dy = 0; dy < 3; ++dy)
        #pragma unroll
        for (int dx = 0; dx < 3; ++dx) {
            int gy = y + dy - 1, gx = x + dx - 1;
            float v = 0.f;
            if ((unsigned)gy < (unsigned)H && (unsigned)gx < (unsigned)W)
                v = in[(size_t)gy * W + gx];
            p[dy * 3 + dx] = v;
        }
    u8* op = out + ((size_t)img * H * W + px) * 64;
    #pragma unroll
    for (int c16 = 0; c16 < 4; ++c16) {
        float v[16];
        #pragma unroll
        for (int c = 0; c < 16; ++c) {
            int co = c16 * 16 + c;
            float a = bias[co];
            #pragma unroll
            for (int k = 0; k < 9; ++k) a += w[co * 9 + k] * p[k];
            v[c] = fmaxf(a, 0.f);
        }
        uint4 o;
        int r;
        r = __builtin_amdgcn_cvt_pk_fp8_f32(v[0], v[1], 0, false);
        o.x = __builtin_amdgcn_cvt_pk_fp8_f32(v[2], v[3], r, true);
        r = __builtin_amdgcn_cvt_pk_fp8_f32(v[4], v[5], 0, false);
        o.y = __builtin_amdgcn_cvt_pk_fp8_f32(v[6], v[7], r, true);
        r = __builtin_amdgcn_cvt_pk_fp8_f32(v[8], v[9], 0, false);
        o.z = __builtin_amdgcn_cvt_pk_fp8_f32(v[10], v[11], r, true);
        r = __builtin_amdgcn_cvt_pk_fp8_f32(v[12], v[13], 0, false);
        o.w = __builtin_amdgcn_cvt_pk_fp8_f32(v[14], v[15], r, true);
        *(uint4*)(op + c16 * 16) = o;
    }
}

// ---------------------------------------------------------------------------
// implicit-GEMM 3x3 SAME conv, NHWC fp8 -> NHWC fp8/bf16, 16x16x32 fp8 MFMA,
// DOUBLE-BUFFERED async staging.
// Block: 4 waves, tile = 64 co x (16y x 16x). Wave wn: 4-row y strip,
// m4n4 = 64 co x 64 px (acc = 4x4 f32x4 = 64 VGPR).
// Fragments (same geometry as R2-verified bf16 16x16x32):
//   A: m(co)=lane&15, k=(lane>>4)*8+j (8 B); B: n(px)=lane&15, same k.
//   C/D: col(px)=lane&15, row(co)=(lane>>4)*4+reg.
// Per 32-ch phase one buffer (chunk c at byte c*16):
//   act: chunk c=p*2+q -> pixel p (18x18 halo) bytes [0,32)   c in [0,648)
//   wt : chunk 648 + t*128 + co*2 + q -> [tap][co][32ch]      c in [648,1800)
//   pad to 2048 chunks = 32768 B; two buffers = 65536 B static LDS.
// K-loop: sync(p) -> issue loads(p+1 -> other buf) -> compute(p).
// EPI: 0 = fp8 store, 1 = fp8 store + fused 2x2 maxpool, 2 = bf16 store,
//      3 = fused perceptual sum((x - fref)^2), no store.
// ---------------------------------------------------------------------------
#define BUF_SZ   32768
#define N_ACT_CH 648
#define N_CHUNK  1800
#define WT_BOFF  10368

template <int CIN, int EPI>
__global__ __launch_bounds__(256, 2) void conv_fp8(
    const u8* __restrict__ in,       // (NIMG, H, W, CIN) fp8
    const u8* __restrict__ wb,       // (CO, 9, CIN) fp8
    const float* __restrict__ bias,  // (CO)
    void* __restrict__ outv,         // fp8 NHWC (EPI0/1, pooled if 1) | bf16 (EPI2)
    int H, int W, int CO,
    const float* __restrict__ zbuf,  // zeroed scratch
    const bf16* __restrict__ fref,   // EPI==3: reference features (bf16)
    float* __restrict__ pacc) {      // EPI==3: perceptual accumulator
    const int tid  = threadIdx.x;
    const int lane = tid & 63;
    const int wn   = tid >> 6;           // 4-row y strip
    const int xl = lane & 15;
    const int kq = lane >> 4;            // k quarter
    const int x0 = blockIdx.x * 16;
    const int y0 = blockIdx.y * 16;
    const int ngrp = CO >> 6;
    const int img = blockIdx.z / ngrp;
    const int co0 = (blockIdx.z - img * ngrp) << 6;

    __shared__ __align__(16) char smem[2 * BUF_SZ];

    f32x4 acc[4][4];
    #pragma unroll
    for (int m = 0; m < 4; ++m)
        #pragma unroll
        for (int n = 0; n < 4; ++n) acc[m][n] = (f32x4){0.f, 0.f, 0.f, 0.f};

    const u8* inp = in + (size_t)img * H * W * CIN;

    // ---- phase-invariant staging sources (chunk c = tid + i*256) ----
    const char* srcp[8];
    unsigned live = 0;
    #pragma unroll
    for (int i = 0; i < 8; ++i) {
        int c = tid + i * 256;
        srcp[i] = (const char*)zbuf;
        if (c < N_ACT_CH) {
            int q = c & 1, p = c >> 1;
            int py = p / 18, px = p - py * 18;
            int gy = y0 - 1 + py, gx = x0 - 1 + px;
            if ((unsigned)gy < (unsigned)H && (unsigned)gx < (unsigned)W) {
                srcp[i] = (const char*)(inp + ((size_t)gy * W + gx) * CIN + q * 16);
                live |= 1u << i;
            }
        } else if (c < N_CHUNK) {
            int c2 = c - N_ACT_CH;
            int t = c2 >> 7, r = c2 & 127, co = r >> 1, q = r & 1;
            srcp[i] = (const char*)(wb + ((size_t)(co0 + co) * 9 + t) * CIN + q * 16);
            live |= 1u << i;
        }
    }

    const int P = CIN / 32;

    // prologue: stage phase 0 into buffer 0
    {
        char* d = smem + tid * 16;
        #pragma unroll
        for (int i = 0; i < 8; ++i) {
            gload_lds16(srcp[i], d + i * 4096);
            if (live & (1u << i)) srcp[i] += 32;
        }
    }

    for (int p = 0; p < P; ++p) {
        __syncthreads();   // drains own loads (issued one compute-phase ago)

        if (p + 1 < P) {   // issue next phase into the other buffer
            char* d = smem + ((p + 1) & 1) * BUF_SZ + tid * 16;
            #pragma unroll
            for (int i = 0; i < 8; ++i) {
                gload_lds16(srcp[i], d + i * 4096);
                if (live & (1u << i)) srcp[i] += 32;
            }
        }

        const char* base = smem + (p & 1) * BUF_SZ;
        const char* aw = base + WT_BOFF + xl * 32 + kq * 8;           // + t*2048 + mt*512
        const char* ba = base + (wn * 4 * 18 + xl) * 32 + kq * 8;     // + ((nt+dy)*18+dx)*32

        #pragma unroll
        for (int t = 0; t < 9; ++t) {
            const int dy = t / 3, dx = t - dy * 3;
            long A[4], B[4];
            #pragma unroll
            for (int mt = 0; mt < 4; ++mt)
                A[mt] = *(const long*)(aw + t * 2048 + mt * 512);
            #pragma unroll
            for (int nt = 0; nt < 4; ++nt)
                B[nt] = *(const long*)(ba + ((nt + dy) * 18 + dx) * 32);
            #pragma unroll
            for (int mt = 0; mt < 4; ++mt)
                #pragma unroll
                for (int nt = 0; nt < 4; ++nt)
                    acc[mt][nt] = __builtin_amdgcn_mfma_f32_16x16x32_fp8_fp8(
                        A[mt], B[nt], acc[mt][nt], 0, 0, 0);
        }
    }

    // ---- epilogue ----
    // C/D: col(px) = lane&15 = xl; row(co within 16) = kq*4 + reg.
    if (EPI == 0) {
        u8* out = (u8*)outv;
        #pragma unroll
        for (int nt = 0; nt < 4; ++nt) {
            const int y = y0 + wn * 4 + nt;
            u8* op = out + (((size_t)img * H + y) * W + (x0 + xl)) * CO;
            #pragma unroll
            for (int mt = 0; mt < 4; ++mt) {
                const int cb = co0 + mt * 16 + kq * 4;
                const f32x4 bv = *(const f32x4*)(bias + cb);
                float v[4];
                #pragma unroll
                for (int r = 0; r < 4; ++r) v[r] = fmaxf(acc[mt][nt][r] + bv[r], 0.f);
                int w0 = __builtin_amdgcn_cvt_pk_fp8_f32(v[0], v[1], 0, false);
                w0 = __builtin_amdgcn_cvt_pk_fp8_f32(v[2], v[3], w0, true);
                *(int*)(op + cb) = w0;
            }
        }
    } else if (EPI == 1) {
        u8* out = (u8*)outv;
        const int Hp = H >> 1, Wp = W >> 1;
        #pragma unroll
        for (int j = 0; j < 2; ++j) {
            const int py = (y0 + wn * 4 + 2 * j) >> 1;
            const int px = (x0 + xl) >> 1;
            #pragma unroll
            for (int mt = 0; mt < 4; ++mt) {
                const int cb = co0 + mt * 16 + kq * 4;
                const f32x4 bv = *(const f32x4*)(bias + cb);
                float v[4];
                #pragma unroll
                for (int r = 0; r < 4; ++r) {
                    float a = acc[mt][2 * j][r] + bv[r];
                    float b = acc[mt][2 * j + 1][r] + bv[r];
                    float m = fmaxf(a, b);
                    m = fmaxf(m, __shfl_xor(m, 1));   // fold x pair
                    v[r] = fmaxf(m, 0.f);
                }
                if (!(lane & 1)) {
                    int w0 = __builtin_amdgcn_cvt_pk_fp8_f32(v[0], v[1], 0, false);
                    w0 = __builtin_amdgcn_cvt_pk_fp8_f32(v[2], v[3], w0, true);
                    *(int*)(out + (((size_t)img * Hp + py) * Wp + px) * CO + cb) = w0;
                }
            }
        }
    } else if (EPI == 2) {
        bf16* out = (bf16*)outv;
        #pragma unroll
        for (int nt = 0; nt < 4; ++nt) {
            const int y = y0 + wn * 4 + nt;
            bf16* op = out + (((size_t)img * H + y) * W + (x0 + xl)) * CO;
            #pragma unroll
            for (int mt = 0; mt < 4; ++mt) {
                const int cb = co0 + mt * 16 + kq * 4;
                const f32x4 bv = *(const f32x4*)(bias + cb);
                us4 o;
                #pragma unroll
                for (int r = 0; r < 4; ++r)
                    o[r] = f2bf(fmaxf(acc[mt][nt][r] + bv[r], 0.f));
                *(us4*)(op + cb) = o;
            }
        }
    } else {
        float s = 0.f;
        #pragma unroll
        for (int nt = 0; nt < 4; ++nt) {
            const int y = y0 + wn * 4 + nt;
            const bf16* fp = fref + (((size_t)img * H + y) * W + (x0 + xl)) * CO;
            #pragma unroll
            for (int mt = 0; mt < 4; ++mt) {
                const int cb = co0 + mt * 16 + kq * 4;
                const f32x4 bv = *(const f32x4*)(bias + cb);
                us4 f = *(const us4*)(fp + cb);
                #pragma unroll
                for (int r = 0; r < 4; ++r) {
                    float v = fmaxf(acc[mt][nt][r] + bv[r], 0.f);
                    float d = bf2f(f2bf(v)) - bf2f(f[r]);
                    s += d * d;
                }
            }
        }
        // block reduce reusing smem (sync first: others may still read LDS)
        #pragma unroll
        for (int o = 32; o > 0; o >>= 1) s += __shfl_down(s, o, 64);
        __syncthreads();
        if (lane == 0) *(float*)(smem + wn * 4) = s;
        __syncthreads();
        if (tid == 0) {
            float tot = *(float*)(smem) + *(float*)(smem + 4) +
                        *(float*)(smem + 8) + *(float*)(smem + 12);
            atomicAdd(pacc, tot);
        }
    }
}

// ---------------------------------------------------------------------------
// launch
// ---------------------------------------------------------------------------
extern "C" void kernel_launch(void* const* d_in, const int* in_sizes, int n_in,
                              void* d_out, int out_size, void* d_ws, size_t ws_size,
                              hipStream_t stream) {
    const float* sr = (const float*)d_in[0];
    const float* hr = (const float*)d_in[1];
    const float* w1 = (const float*)d_in[2];
    const float* b1 = (const float*)d_in[3];
    const float* w2 = (const float*)d_in[4];
    const float* b2 = (const float*)d_in[5];
    const float* w3 = (const float*)d_in[6];
    const float* b3 = (const float*)d_in[7];
    const float* w4 = (const float*)d_in[8];
    const float* b4 = (const float*)d_in[9];
    float* out = (float*)d_out;

    char* ws = (char*)d_ws;
    size_t off = 0;
    float* accs = (float*)(ws + off); off += 256;
    float* zbuf = (float*)(ws + off); off += 256;
    u8* wb2 = (u8*)(ws + off); off += (size_t)128 * 9 * 64;
    u8* wb3 = (u8*)(ws + off); off += (size_t)256 * 9 * 128;
    u8* wb4 = (u8*)(ws + off); off += (size_t)256 * 9 * 256;
    const size_t fixed = (off + 255) & ~(size_t)255;

    const size_t MB = 1024u * 1024u;
    // per image: A 4MB (fp8), P 2MB (fp8), F 8MB (bf16) = 14MB
    int nb = 8;
    while (nb > 1 && fixed + (size_t)nb * 14 * MB > ws_size) nb >>= 1;

    u8*   A = (u8*)(ws + fixed);                          // (nb,256,256,64)|(nb,128,128,256) fp8
    u8*   P = (u8*)(ws + fixed + (size_t)nb * 4 * MB);    // (nb,128,128,128) fp8
    bf16* F = (bf16*)(ws + fixed + (size_t)nb * 6 * MB);  // (nb,128,128,256) bf16

    zero_accs_kernel<<<1, 64, 0, stream>>>(accs, zbuf);
    wprep_fp8_kernel<<<144, 256, 0, stream>>>(w2, wb2, 64, 128);
    wprep_fp8_kernel<<<576, 256, 0, stream>>>(w3, wb3, 128, 256);
    wprep_fp8_kernel<<<1152, 256, 0, stream>>>(w4, wb4, 256, 256);
    mse_kernel<<<2048, 256, 0, stream>>>(sr, hr, accs + 0, 524288);
    ssim_kernel<<<dim3(245, 8), 256, 0, stream>>>(sr, hr, accs + 1);

    for (int b0 = 0; b0 < 8; b0 += nb) {
        // ---- sr pass: features -> F (bf16) ----
        conv1_kernel<<<dim3(256, nb), 256, 0, stream>>>(sr + (size_t)b0 * 65536, w1, b1, A);
        conv_fp8<64, 1><<<dim3(16, 16, nb * 2), 256, 0, stream>>>(
            A, wb2, b2, P, 256, 256, 128, zbuf, nullptr, nullptr);
        conv_fp8<128, 0><<<dim3(8, 8, nb * 4), 256, 0, stream>>>(
            P, wb3, b3, A, 128, 128, 256, zbuf, nullptr, nullptr);
        conv_fp8<256, 2><<<dim3(8, 8, nb * 4), 256, 0, stream>>>(
            A, wb4, b4, F, 128, 128, 256, zbuf, nullptr, nullptr);
        // ---- hr pass: features, fused perceptual vs F ----
        conv1_kernel<<<dim3(256, nb), 256, 0, stream>>>(hr + (size_t)b0 * 65536, w1, b1, A);
        conv_fp8<64, 1><<<dim3(16, 16, nb * 2), 256, 0, stream>>>(
            A, wb2, b2, P, 256, 256, 128, zbuf, nullptr, nullptr);
        conv_fp8<128, 0><<<dim3(8, 8, nb * 4), 256, 0, stream>>>(
            P, wb3, b3, A, 128, 128, 256, zbuf, nullptr, nullptr);
        conv_fp8<256, 3><<<dim3(8, 8, nb * 4), 256, 0, stream>>>(
            A, wb4, b4, nullptr, 128, 128, 256, zbuf, F, accs + 2);
    }

    finalize_kernel<<<1, 1, 0, stream>>>(accs, out);
}

// Round 9
// 561.834 us; speedup vs baseline: 2.7208x; 1.2655x over previous
//
#include <hip/hip_runtime.h>
#include <hip/hip_bf16.h>

typedef __hip_bfloat16 bf16;
typedef unsigned char u8;
typedef __attribute__((ext_vector_type(4))) float f32x4;
typedef __attribute__((ext_vector_type(4))) unsigned short us4;
typedef __attribute__((ext_vector_type(8))) unsigned short us8;

__device__ inline unsigned short f2bf(float f) {
    __hip_bfloat16 h = __float2bfloat16(f);
    return __builtin_bit_cast(unsigned short, h);
}
__device__ inline float bf2f(unsigned short u) {
    unsigned int x = ((unsigned int)u) << 16;
    return __builtin_bit_cast(float, x);
}

// async global->LDS 16B copy; LDS dst must be wave-uniform base + lane*16
typedef __attribute__((address_space(3))) unsigned int lds_uint;
typedef __attribute__((address_space(1))) const unsigned int g_uint;
__device__ inline void gload_lds16(const void* g, void* l) {
    __builtin_amdgcn_global_load_lds((g_uint*)g, (lds_uint*)l, 16, 0, 0);
}

__device__ inline void block_reduce_atomic(float v, float* dst) {
    #pragma unroll
    for (int o = 32; o > 0; o >>= 1) v += __shfl_down(v, o, 64);
    __shared__ float ws[8];
    const int lane = threadIdx.x & 63;
    const int wid  = threadIdx.x >> 6;
    if (lane == 0) ws[wid] = v;
    __syncthreads();
    if (threadIdx.x == 0) {
        float s = 0.f;
        const int nw = (blockDim.x + 63) >> 6;
        for (int i = 0; i < nw; ++i) s += ws[i];
        atomicAdd(dst, s);
    }
}

// ---------------------------------------------------------------------------
// small kernels
// ---------------------------------------------------------------------------
__global__ void zero_accs_kernel(float* accs, float* zbuf) {
    if (threadIdx.x < 8)  accs[threadIdx.x] = 0.f;
    if (threadIdx.x < 64) zbuf[threadIdx.x] = 0.f;
}

__global__ void mse_kernel(const float* __restrict__ a, const float* __restrict__ b,
                           float* __restrict__ acc, int n) {
    float s = 0.f;
    for (int i = blockIdx.x * blockDim.x + threadIdx.x; i < n; i += gridDim.x * blockDim.x) {
        float d = a[i] - b[i];
        s += d * d;
    }
    block_reduce_atomic(s, acc);
}

__global__ void ssim_kernel(const float* __restrict__ x, const float* __restrict__ y,
                            float* __restrict__ acc) {
    const int b = blockIdx.y;
    const int t = blockIdx.x * blockDim.x + threadIdx.x;
    float S = 0.f;
    if (t < 250 * 250) {
        const int i = t / 250, j = t - (t / 250) * 250;
        const float* xp = x + (size_t)b * 65536;
        const float* yp = y + (size_t)b * 65536;
        float sx = 0.f, sy = 0.f, sxx = 0.f, syy = 0.f, sxy = 0.f;
        #pragma unroll
        for (int dy = 0; dy < 7; ++dy) {
            const float* xr = xp + (size_t)(i + dy) * 256 + j;
            const float* yr = yp + (size_t)(i + dy) * 256 + j;
            #pragma unroll
            for (int dx = 0; dx < 7; ++dx) {
                float a = xr[dx], c = yr[dx];
                sx += a; sy += c;
                sxx += a * a; syy += c * c; sxy += a * c;
            }
        }
        const float inv = 1.f / 49.f;
        const float cn  = 49.f / 48.f;
        float ux = sx * inv, uy = sy * inv;
        float vx  = cn * (sxx * inv - ux * ux);
        float vy  = cn * (syy * inv - uy * uy);
        float vxy = cn * (sxy * inv - ux * uy);
        const float C1 = 1e-4f, C2 = 9e-4f;
        S = ((2.f * ux * uy + C1) * (2.f * vxy + C2)) /
            ((ux * ux + uy * uy + C1) * (vx + vy + C2));
    }
    block_reduce_atomic(S, acc);
}

__global__ void finalize_kernel(const float* __restrict__ accs, float* __restrict__ out) {
    if (threadIdx.x == 0) {
        float mse    = accs[0] * (1.f / 524288.f);
        float ssim_l = 1.f - accs[1] * (1.f / 500000.f);
        float perc   = accs[2] * (1.f / 33554432.f);
        out[0] = mse + 0.5f * ssim_l + 0.1f * perc;
        out[1] = mse;
        out[2] = ssim_l;
        out[3] = perc;
    }
}

// repack weights (CO,CIN,3,3) fp32 -> [phase p][tap t][kq][co][8ch] fp8 e4m3
// (ci = p*32 + kq*8 + j)
__global__ void wprep_fp8_kernel(const float* __restrict__ w, u8* __restrict__ wb,
                                 int CIN, int CO) {
    int idx = blockIdx.x * blockDim.x + threadIdx.x;   // one fp8 PAIR
    int n2 = CO * 9 * CIN / 2;
    if (idx >= n2) return;
    int e = idx * 2;
    int j  = e & 7;                     // even
    int co = (e >> 3) % CO;
    int kq = (e / (8 * CO)) & 3;
    int t  = (e / (32 * CO)) % 9;
    int p  = e / (288 * CO);
    int ci = p * 32 + kq * 8 + j;
    float v0 = w[((size_t)co * CIN + ci) * 9 + t];
    float v1 = w[((size_t)co * CIN + ci + 1) * 9 + t];
    int r = __builtin_amdgcn_cvt_pk_fp8_f32(v0, v1, 0, false);
    *(unsigned short*)(wb + e) = (unsigned short)(r & 0xffff);
}

// ---------------------------------------------------------------------------
// conv1: CIN=1, CO=64, fp32 NCHW in -> fp8 planar NC8HW8 out, relu
// out layout: [img][plane g=co/8][H*W][8ch]
// ---------------------------------------------------------------------------
__global__ __launch_bounds__(256) void conv1_kernel(
    const float* __restrict__ in0, const float* __restrict__ w,
    const float* __restrict__ bias, u8* __restrict__ out) {
    const int H = 256, W = 256;
    const int img = blockIdx.y;
    const float* in = in0 + (size_t)img * 65536;
    int px = blockIdx.x * 256 + threadIdx.x;
    int y = px >> 8, x = px & 255;
    float p[9];
    #pragma unroll
    for (int dy = 0; dy < 3; ++dy)
        #pragma unroll
        for (int dx = 0; dx < 3; ++dx) {
            int gy = y + dy - 1, gx = x + dx - 1;
            float v = 0.f;
            if ((unsigned)gy < (unsigned)H && (unsigned)gx < (unsigned)W)
                v = in[(size_t)gy * W + gx];
            p[dy * 3 + dx] = v;
        }
    #pragma unroll
    for (int g = 0; g < 8; ++g) {
        float v[8];
        #pragma unroll
        for (int c = 0; c < 8; ++c) {
            int co = g * 8 + c;
            float a = bias[co];
            #pragma unroll
            for (int k = 0; k < 9; ++k) a += w[co * 9 + k] * p[k];
            v[c] = fmaxf(a, 0.f);
        }
        uint2 o;
        int r;
        r = __builtin_amdgcn_cvt_pk_fp8_f32(v[0], v[1], 0, false);
        o.x = __builtin_amdgcn_cvt_pk_fp8_f32(v[2], v[3], r, true);
        r = __builtin_amdgcn_cvt_pk_fp8_f32(v[4], v[5], 0, false);
        o.y = __builtin_amdgcn_cvt_pk_fp8_f32(v[6], v[7], r, true);
        *(uint2*)(out + (((size_t)img * 8 + g) * 65536 + px) * 8) = o;
    }
}

// ---------------------------------------------------------------------------
// implicit-GEMM 3x3 SAME conv, planar-fp8 in -> planar-fp8 / bf16 out,
// 16x16x32 fp8 MFMA, double-buffered async staging, CONFLICT-FREE LDS:
// every 16-lane kq-group reads contiguous 8-B runs (covers all 32 banks).
// Block: 4 waves, tile = 64 co x (16y x 16x). Wave wn: 4-row strip, m4n4.
// Input global layout: planar [img][CIN/8 planes][H*W][8ch].
// Per 32-ch phase one buffer (chunk c at byte c*16):
//   act c in [0,720):   g=c/180, r=c%180, row=r/10, pp=r%10
//                       = plane g (kq), 18 rows x 20 cols halo (x0-2..x0+17)
//   wt  c in [720,1872): c2=c-720: t=c2/128, kq=(c2>>5)&3, copair=c2&31
//   buffer = 2048 chunks = 32768 B; two buffers = 65536 B static LDS.
// K-loop: sync(p) -> issue loads(p+1 -> other buf) -> compute(p).
// EPI: 0 = planar fp8 store, 1 = planar fp8 + fused 2x2 maxpool,
//      2 = bf16 NHWC store, 3 = fused perceptual sum((x-fref)^2), no store.
// ---------------------------------------------------------------------------
#define BUF_SZ   32768
#define N_ACT_CH 720
#define N_CHUNK  1872
#define WT_BOFF  11520

template <int CIN, int EPI>
__global__ __launch_bounds__(256, 2) void conv_fp8(
    const u8* __restrict__ in,       // planar fp8
    const u8* __restrict__ wb,       // [phase][t][kq][co][8] fp8
    const float* __restrict__ bias,  // (CO)
    void* __restrict__ outv,
    int H, int W, int CO,
    const float* __restrict__ zbuf,  // zeroed scratch
    const bf16* __restrict__ fref,   // EPI==3: reference features (bf16 NHWC)
    float* __restrict__ pacc) {      // EPI==3: perceptual accumulator
    const int tid  = threadIdx.x;
    const int lane = tid & 63;
    const int wn   = tid >> 6;           // 4-row y strip
    const int xl = lane & 15;
    const int kq = lane >> 4;            // k octet group
    const int x0 = blockIdx.x * 16;
    const int y0 = blockIdx.y * 16;
    const int ngrp = CO >> 6;
    const int img = blockIdx.z / ngrp;
    const int co0 = (blockIdx.z - img * ngrp) << 6;

    __shared__ __align__(16) char smem[2 * BUF_SZ];

    f32x4 acc[4][4];
    #pragma unroll
    for (int m = 0; m < 4; ++m)
        #pragma unroll
        for (int n = 0; n < 4; ++n) acc[m][n] = (f32x4){0.f, 0.f, 0.f, 0.f};

    const size_t HW = (size_t)H * W;
    const u8* inp = in + (size_t)img * (CIN >> 3) * HW * 8;

    // ---- phase-invariant staging sources (chunk c = tid + i*256) ----
    const char* srcp[8];
    long adv[8];
    #pragma unroll
    for (int i = 0; i < 8; ++i) {
        int c = tid + i * 256;
        srcp[i] = (const char*)zbuf;
        adv[i] = 0;
        if (c < N_ACT_CH) {
            int g = c / 180, r = c - g * 180;
            int row = r / 10, pp = r - row * 10;
            int gy = y0 - 1 + row, colb = x0 - 2 + pp * 2;
            if ((unsigned)gy < (unsigned)H && (unsigned)colb < (unsigned)(W - 1)) {
                srcp[i] = (const char*)(inp + ((size_t)g * HW + (size_t)gy * W + colb) * 8);
                adv[i] = 4 * HW * 8;          // next phase: +4 planes
            }
        } else if (c < N_CHUNK) {
            int c2 = c - N_ACT_CH;
            int t = c2 >> 7, kqc = (c2 >> 5) & 3, cp = c2 & 31;
            srcp[i] = (const char*)(wb + (((size_t)t * 4 + kqc) * CO + co0 + cp * 2) * 8);
            adv[i] = 288 * CO;                // 9*4*CO*8 bytes per phase
        }
    }

    const int P = CIN / 32;

    // prologue: stage phase 0 into buffer 0
    {
        char* d = smem + tid * 16;
        #pragma unroll
        for (int i = 0; i < 8; ++i) {
            gload_lds16(srcp[i], d + i * 4096);
            srcp[i] += adv[i];
        }
    }

    for (int p = 0; p < P; ++p) {
        __syncthreads();   // drains own loads (issued one compute-phase ago)

        if (p + 1 < P) {   // issue next phase into the other buffer
            char* d = smem + ((p + 1) & 1) * BUF_SZ + tid * 16;
            #pragma unroll
            for (int i = 0; i < 8; ++i) {
                gload_lds16(srcp[i], d + i * 4096);
                srcp[i] += adv[i];
            }
        }

        const char* base = smem + (p & 1) * BUF_SZ;
        const char* aw = base + WT_BOFF + kq * 512 + xl * 8;            // +t*2048 +mt*128
        const char* ba = base + kq * 2880 + ((wn * 4) * 20 + xl + 1) * 8; // +((nt+dy)*20+dx)*8

        #pragma unroll
        for (int t = 0; t < 9; ++t) {
            const int dy = t / 3, dx = t - dy * 3;
            long A[4], B[4];
            #pragma unroll
            for (int mt = 0; mt < 4; ++mt)
                A[mt] = *(const long*)(aw + t * 2048 + mt * 128);
            #pragma unroll
            for (int nt = 0; nt < 4; ++nt)
                B[nt] = *(const long*)(ba + ((nt + dy) * 20 + dx) * 8);
            #pragma unroll
            for (int mt = 0; mt < 4; ++mt)
                #pragma unroll
                for (int nt = 0; nt < 4; ++nt)
                    acc[mt][nt] = __builtin_amdgcn_mfma_f32_16x16x32_fp8_fp8(
                        A[mt], B[nt], acc[mt][nt], 0, 0, 0);
        }
    }

    // ---- epilogue ----
    // C/D: col(px) = lane&15 = xl; row(co within 16) = kq*4 + reg.
    if (EPI == 0) {
        u8* out = (u8*)outv;
        #pragma unroll
        for (int nt = 0; nt < 4; ++nt) {
            const int y = y0 + wn * 4 + nt;
            #pragma unroll
            for (int mt = 0; mt < 4; ++mt) {
                const int cb = co0 + mt * 16 + kq * 4;
                const f32x4 bv = *(const f32x4*)(bias + cb);
                float v[4];
                #pragma unroll
                for (int r = 0; r < 4; ++r) v[r] = fmaxf(acc[mt][nt][r] + bv[r], 0.f);
                int w0 = __builtin_amdgcn_cvt_pk_fp8_f32(v[0], v[1], 0, false);
                w0 = __builtin_amdgcn_cvt_pk_fp8_f32(v[2], v[3], w0, true);
                *(int*)(out + (((size_t)img * (CO >> 3) + (cb >> 3)) * HW +
                               (size_t)y * W + x0 + xl) * 8 + (cb & 7)) = w0;
            }
        }
    } else if (EPI == 1) {
        u8* out = (u8*)outv;
        const int Hp = H >> 1, Wp = W >> 1;
        const size_t HWp = (size_t)Hp * Wp;
        #pragma unroll
        for (int j = 0; j < 2; ++j) {
            const int py = (y0 + wn * 4 + 2 * j) >> 1;
            const int px = (x0 + xl) >> 1;
            #pragma unroll
            for (int mt = 0; mt < 4; ++mt) {
                const int cb = co0 + mt * 16 + kq * 4;
                const f32x4 bv = *(const f32x4*)(bias + cb);
                float v[4];
                #pragma unroll
                for (int r = 0; r < 4; ++r) {
                    float a = acc[mt][2 * j][r] + bv[r];
                    float b = acc[mt][2 * j + 1][r] + bv[r];
                    float m = fmaxf(a, b);
                    m = fmaxf(m, __shfl_xor(m, 1));   // fold x pair
                    v[r] = fmaxf(m, 0.f);
                }
                if (!(lane & 1)) {
                    int w0 = __builtin_amdgcn_cvt_pk_fp8_f32(v[0], v[1], 0, false);
                    w0 = __builtin_amdgcn_cvt_pk_fp8_f32(v[2], v[3], w0, true);
                    *(int*)(out + (((size_t)img * (CO >> 3) + (cb >> 3)) * HWp +
                                   (size_t)py * Wp + px) * 8 + (cb & 7)) = w0;
                }
            }
        }
    } else if (EPI == 2) {
        bf16* out = (bf16*)outv;
        #pragma unroll
        for (int nt = 0; nt < 4; ++nt) {
            const int y = y0 + wn * 4 + nt;
            bf16* op = out + (((size_t)img * H + y) * W + (x0 + xl)) * CO;
            #pragma unroll
            for (int mt = 0; mt < 4; ++mt) {
                const int cb = co0 + mt * 16 + kq * 4;
                const f32x4 bv = *(const f32x4*)(bias + cb);
                us4 o;
                #pragma unroll
                for (int r = 0; r < 4; ++r)
                    o[r] = f2bf(fmaxf(acc[mt][nt][r] + bv[r], 0.f));
                *(us4*)(op + cb) = o;
            }
        }
    } else {
        float s = 0.f;
        #pragma unroll
        for (int nt = 0; nt < 4; ++nt) {
            const int y = y0 + wn * 4 + nt;
            const bf16* fp = fref + (((size_t)img * H + y) * W + (x0 + xl)) * CO;
            #pragma unroll
            for (int mt = 0; mt < 4; ++mt) {
                const int cb = co0 + mt * 16 + kq * 4;
                const f32x4 bv = *(const f32x4*)(bias + cb);
                us4 f = *(const us4*)(fp + cb);
                #pragma unroll
                for (int r = 0; r < 4; ++r) {
                    float v = fmaxf(acc[mt][nt][r] + bv[r], 0.f);
                    float d = bf2f(f2bf(v)) - bf2f(f[r]);
                    s += d * d;
                }
            }
        }
        // block reduce reusing smem (sync first: others may still read LDS)
        #pragma unroll
        for (int o = 32; o > 0; o >>= 1) s += __shfl_down(s, o, 64);
        __syncthreads();
        if (lane == 0) *(float*)(smem + wn * 4) = s;
        __syncthreads();
        if (tid == 0) {
            float tot = *(float*)(smem) + *(float*)(smem + 4) +
                        *(float*)(smem + 8) + *(float*)(smem + 12);
            atomicAdd(pacc, tot);
        }
    }
}

// ---------------------------------------------------------------------------
// launch
// ---------------------------------------------------------------------------
extern "C" void kernel_launch(void* const* d_in, const int* in_sizes, int n_in,
                              void* d_out, int out_size, void* d_ws, size_t ws_size,
                              hipStream_t stream) {
    const float* sr = (const float*)d_in[0];
    const float* hr = (const float*)d_in[1];
    const float* w1 = (const float*)d_in[2];
    const float* b1 = (const float*)d_in[3];
    const float* w2 = (const float*)d_in[4];
    const float* b2 = (const float*)d_in[5];
    const float* w3 = (const float*)d_in[6];
    const float* b3 = (const float*)d_in[7];
    const float* w4 = (const float*)d_in[8];
    const float* b4 = (const float*)d_in[9];
    float* out = (float*)d_out;

    char* ws = (char*)d_ws;
    size_t off = 0;
    float* accs = (float*)(ws + off); off += 256;
    float* zbuf = (float*)(ws + off); off += 256;
    u8* wb2 = (u8*)(ws + off); off += (size_t)128 * 9 * 64;
    u8* wb3 = (u8*)(ws + off); off += (size_t)256 * 9 * 128;
    u8* wb4 = (u8*)(ws + off); off += (size_t)256 * 9 * 256;
    const size_t fixed = (off + 255) & ~(size_t)255;

    const size_t MB = 1024u * 1024u;
    // per image: A 4MB (fp8 planar), P 2MB (fp8 planar), F 8MB (bf16) = 14MB
    int nb = 8;
    while (nb > 1 && fixed + (size_t)nb * 14 * MB > ws_size) nb >>= 1;

    u8*   A = (u8*)(ws + fixed);                          // fp8 planar
    u8*   P = (u8*)(ws + fixed + (size_t)nb * 4 * MB);    // fp8 planar pooled
    bf16* F = (bf16*)(ws + fixed + (size_t)nb * 6 * MB);  // bf16 NHWC

    zero_accs_kernel<<<1, 64, 0, stream>>>(accs, zbuf);
    wprep_fp8_kernel<<<144, 256, 0, stream>>>(w2, wb2, 64, 128);
    wprep_fp8_kernel<<<576, 256, 0, stream>>>(w3, wb3, 128, 256);
    wprep_fp8_kernel<<<1152, 256, 0, stream>>>(w4, wb4, 256, 256);
    mse_kernel<<<2048, 256, 0, stream>>>(sr, hr, accs + 0, 524288);
    ssim_kernel<<<dim3(245, 8), 256, 0, stream>>>(sr, hr, accs + 1);

    for (int b0 = 0; b0 < 8; b0 += nb) {
        // ---- sr pass: features -> F (bf16) ----
        conv1_kernel<<<dim3(256, nb), 256, 0, stream>>>(sr + (size_t)b0 * 65536, w1, b1, A);
        conv_fp8<64, 1><<<dim3(16, 16, nb * 2), 256, 0, stream>>>(
            A, wb2, b2, P, 256, 256, 128, zbuf, nullptr, nullptr);
        conv_fp8<128, 0><<<dim3(8, 8, nb * 4), 256, 0, stream>>>(
            P, wb3, b3, A, 128, 128, 256, zbuf, nullptr, nullptr);
        conv_fp8<256, 2><<<dim3(8, 8, nb * 4), 256, 0, stream>>>(
            A, wb4, b4, F, 128, 128, 256, zbuf, nullptr, nullptr);
        // ---- hr pass: features, fused perceptual vs F ----
        conv1_kernel<<<dim3(256, nb), 256, 0, stream>>>(hr + (size_t)b0 * 65536, w1, b1, A);
        conv_fp8<64, 1><<<dim3(16, 16, nb * 2), 256, 0, stream>>>(
            A, wb2, b2, P, 256, 256, 128, zbuf, nullptr, nullptr);
        conv_fp8<128, 0><<<dim3(8, 8, nb * 4), 256, 0, stream>>>(
            P, wb3, b3, A, 128, 128, 256, zbuf, nullptr, nullptr);
        conv_fp8<256, 3><<<dim3(8, 8, nb * 4), 256, 0, stream>>>(
            A, wb4, b4, nullptr, 128, 128, 256, zbuf, F, accs + 2);
    }

    finalize_kernel<<<1, 1, 0, stream>>>(accs, out);
}

// Round 10
// 500.412 us; speedup vs baseline: 3.0547x; 1.1227x over previous
//
#include <hip/hip_runtime.h>
#include <hip/hip_bf16.h>

typedef __hip_bfloat16 bf16;
typedef unsigned char u8;
typedef __attribute__((ext_vector_type(4))) float f32x4;
typedef __attribute__((ext_vector_type(4))) unsigned short us4;
typedef __attribute__((ext_vector_type(8))) unsigned short us8;
typedef __attribute__((ext_vector_type(8))) int i32x8;
typedef __attribute__((ext_vector_type(4))) unsigned int u32x4;

struct L4 { long a, b, c, d; };
struct U2 { u32x4 x, y; };

__device__ inline unsigned short f2bf(float f) {
    __hip_bfloat16 h = __float2bfloat16(f);
    return __builtin_bit_cast(unsigned short, h);
}
__device__ inline float bf2f(unsigned short u) {
    unsigned int x = ((unsigned int)u) << 16;
    return __builtin_bit_cast(float, x);
}

// async global->LDS 16B copy; LDS dst must be wave-uniform base + lane*16
typedef __attribute__((address_space(3))) unsigned int lds_uint;
typedef __attribute__((address_space(1))) const unsigned int g_uint;
__device__ inline void gload_lds16(const void* g, void* l) {
    __builtin_amdgcn_global_load_lds((g_uint*)g, (lds_uint*)l, 16, 0, 0);
}

__device__ inline void block_reduce_atomic(float v, float* dst) {
    #pragma unroll
    for (int o = 32; o > 0; o >>= 1) v += __shfl_down(v, o, 64);
    __shared__ float ws[8];
    const int lane = threadIdx.x & 63;
    const int wid  = threadIdx.x >> 6;
    if (lane == 0) ws[wid] = v;
    __syncthreads();
    if (threadIdx.x == 0) {
        float s = 0.f;
        const int nw = (blockDim.x + 63) >> 6;
        for (int i = 0; i < nw; ++i) s += ws[i];
        atomicAdd(dst, s);
    }
}

// ---------------------------------------------------------------------------
// small kernels
// ---------------------------------------------------------------------------
__global__ void zero_accs_kernel(float* accs, float* zbuf) {
    if (threadIdx.x < 8)  accs[threadIdx.x] = 0.f;
    if (threadIdx.x < 64) zbuf[threadIdx.x] = 0.f;
}

__global__ void mse_kernel(const float* __restrict__ a, const float* __restrict__ b,
                           float* __restrict__ acc, int n) {
    float s = 0.f;
    for (int i = blockIdx.x * blockDim.x + threadIdx.x; i < n; i += gridDim.x * blockDim.x) {
        float d = a[i] - b[i];
        s += d * d;
    }
    block_reduce_atomic(s, acc);
}

__global__ void ssim_kernel(const float* __restrict__ x, const float* __restrict__ y,
                            float* __restrict__ acc) {
    const int b = blockIdx.y;
    const int t = blockIdx.x * blockDim.x + threadIdx.x;
    float S = 0.f;
    if (t < 250 * 250) {
        const int i = t / 250, j = t - (t / 250) * 250;
        const float* xp = x + (size_t)b * 65536;
        const float* yp = y + (size_t)b * 65536;
        float sx = 0.f, sy = 0.f, sxx = 0.f, syy = 0.f, sxy = 0.f;
        #pragma unroll
        for (int dy = 0; dy < 7; ++dy) {
            const float* xr = xp + (size_t)(i + dy) * 256 + j;
            const float* yr = yp + (size_t)(i + dy) * 256 + j;
            #pragma unroll
            for (int dx = 0; dx < 7; ++dx) {
                float a = xr[dx], c = yr[dx];
                sx += a; sy += c;
                sxx += a * a; syy += c * c; sxy += a * c;
            }
        }
        const float inv = 1.f / 49.f;
        const float cn  = 49.f / 48.f;
        float ux = sx * inv, uy = sy * inv;
        float vx  = cn * (sxx * inv - ux * ux);
        float vy  = cn * (syy * inv - uy * uy);
        float vxy = cn * (sxy * inv - ux * uy);
        const float C1 = 1e-4f, C2 = 9e-4f;
        S = ((2.f * ux * uy + C1) * (2.f * vxy + C2)) /
            ((ux * ux + uy * uy + C1) * (vx + vy + C2));
    }
    block_reduce_atomic(S, acc);
}

__global__ void finalize_kernel(const float* __restrict__ accs, float* __restrict__ out) {
    if (threadIdx.x == 0) {
        float mse    = accs[0] * (1.f / 524288.f);
        float ssim_l = 1.f - accs[1] * (1.f / 500000.f);
        float perc   = accs[2] * (1.f / 33554432.f);
        out[0] = mse + 0.5f * ssim_l + 0.1f * perc;
        out[1] = mse;
        out[2] = ssim_l;
        out[3] = perc;
    }
}

// repack weights (CO,CIN,3,3) fp32 -> per-32ch-phase MX-packed fp8 e4m3:
// per phase p: [t(0..7)][q(0/1: 16-ch half)][CO][16 B]  (256*CO bytes)
//              then tap8: [q(0/1)][CO][16 B]            (32*CO bytes)
__global__ void wprep_mx_kernel(const float* __restrict__ w, u8* __restrict__ wb,
                                int CIN, int CO) {
    int idx = blockIdx.x * blockDim.x + threadIdx.x;
    int n = CO * 9 * CIN;
    if (idx >= n) return;
    int t = idx % 9;
    int rest = idx / 9;
    int ci = rest % CIN;
    int co = rest / CIN;
    float v = w[idx];            // w flat = ((co*CIN+ci)*9 + t)
    int p = ci >> 5, c32 = ci & 31;
    size_t off = (size_t)p * 288 * CO;
    if (t < 8) {
        off += (((size_t)t * 2 + (c32 >> 4)) * CO + co) * 16 + (c32 & 15);
    } else {
        off += 256 * (size_t)CO + (((size_t)(c32 >> 4)) * CO + co) * 16 + (c32 & 15);
    }
    int r = __builtin_amdgcn_cvt_pk_fp8_f32(v, v, 0, false);
    wb[off] = (u8)(r & 0xff);
}

// ---------------------------------------------------------------------------
// conv1: CIN=1, CO=64, fp32 NCHW in -> fp8 planar NC8HW8 out, relu
// out layout: [img][plane g=co/8][H*W][8ch]
// ---------------------------------------------------------------------------
__global__ __launch_bounds__(256) void conv1_kernel(
    const float* __restrict__ in0, const float* __restrict__ w,
    const float* __restrict__ bias, u8* __restrict__ out) {
    const int H = 256, W = 256;
    const int img = blockIdx.y;
    const float* in = in0 + (size_t)img * 65536;
    int px = blockIdx.x * 256 + threadIdx.x;
    int y = px >> 8, x = px & 255;
    float p[9];
    #pragma unroll
    for (int dy = 0; dy < 3; ++dy)
        #pragma unroll
        for (int dx = 0; dx < 3; ++dx) {
            int gy = y + dy - 1, gx = x + dx - 1;
            float v = 0.f;
            if ((unsigned)gy < (unsigned)H && (unsigned)gx < (unsigned)W)
                v = in[(size_t)gy * W + gx];
            p[dy * 3 + dx] = v;
        }
    #pragma unroll
    for (int g = 0; g < 8; ++g) {
        float v[8];
        #pragma unroll
        for (int c = 0; c < 8; ++c) {
            int co = g * 8 + c;
            float a = bias[co];
            #pragma unroll
            for (int k = 0; k < 9; ++k) a += w[co * 9 + k] * p[k];
            v[c] = fmaxf(a, 0.f);
        }
        uint2 o;
        int r;
        r = __builtin_amdgcn_cvt_pk_fp8_f32(v[0], v[1], 0, false);
        o.x = __builtin_amdgcn_cvt_pk_fp8_f32(v[2], v[3], r, true);
        r = __builtin_amdgcn_cvt_pk_fp8_f32(v[4], v[5], 0, false);
        o.y = __builtin_amdgcn_cvt_pk_fp8_f32(v[6], v[7], r, true);
        *(uint2*)(out + (((size_t)img * 8 + g) * 65536 + px) * 8) = o;
    }
}

// ---------------------------------------------------------------------------
// implicit-GEMM 3x3 SAME conv, planar-fp8 in -> planar-fp8 / bf16 out.
// MX-scaled 16x16x128 f8f6f4 MFMA with TAP-PACKED K: one MFMA covers
// 4 taps x 32 ch (k = tap_in_group*32 + ch; lane's k-block = lane>>4 picks
// its tap, so the tap spatial shift is a per-lane LDS address offset).
// Taps 0-3, 4-7 = two MX steps; tap 8 = one plain fp8 16x16x32 step.
// Unit e8m0 scales (0x7F) => pure fp8 math at 2x the MFMA rate.
// Block: 4 waves, tile = 64 co x (16y x 16x), wave m4n4; dbuf async staging
// identical to R9 (1872 chunks/phase): act planar [q][18row][10colpair][16B],
// wt [t<8][q][co][16B] + tap8 [q][co][16B]. All LDS reads conflict-free.
// EPI: 0 = planar fp8 store, 1 = planar fp8 + fused 2x2 maxpool,
//      2 = bf16 NHWC store, 3 = fused perceptual sum((x-fref)^2), no store.
// ---------------------------------------------------------------------------
#define BUF_SZ   32768
#define N_ACT_CH 720
#define N_CHUNK  1872
#define WT_BOFF  11520     // 720*16
#define W8_BOFF  27904     // (720+1024)*16

template <int CIN, int EPI>
__global__ __launch_bounds__(256, 2) void conv_mx(
    const u8* __restrict__ in,       // planar fp8
    const u8* __restrict__ wb,       // MX-packed weights (see wprep)
    const float* __restrict__ bias,  // (CO)
    void* __restrict__ outv,
    int H, int W, int CO,
    const float* __restrict__ zbuf,  // zeroed scratch
    const bf16* __restrict__ fref,   // EPI==3: reference features (bf16 NHWC)
    float* __restrict__ pacc) {      // EPI==3: perceptual accumulator
    const int tid  = threadIdx.x;
    const int lane = tid & 63;
    const int wn   = tid >> 6;           // 4-row y strip
    const int xl = lane & 15;
    const int kq = lane >> 4;            // MX: tap-in-group; tap8: ch octet
    const int x0 = blockIdx.x * 16;
    const int y0 = blockIdx.y * 16;
    const int ngrp = CO >> 6;
    const int img = blockIdx.z / ngrp;
    const int co0 = (blockIdx.z - img * ngrp) << 6;

    __shared__ __align__(16) char smem[2 * BUF_SZ];

    f32x4 acc[4][4];
    #pragma unroll
    for (int m = 0; m < 4; ++m)
        #pragma unroll
        for (int n = 0; n < 4; ++n) acc[m][n] = (f32x4){0.f, 0.f, 0.f, 0.f};

    const size_t HW = (size_t)H * W;
    const u8* inp = in + (size_t)img * (CIN >> 3) * HW * 8;

    // ---- phase-invariant staging sources (chunk c = tid + i*256) ----
    const char* srcp[8];
    long adv[8];
    #pragma unroll
    for (int i = 0; i < 8; ++i) {
        int c = tid + i * 256;
        srcp[i] = (const char*)zbuf;
        adv[i] = 0;
        if (c < N_ACT_CH) {
            int g = c / 180, r = c - g * 180;
            int row = r / 10, pp = r - row * 10;
            int gy = y0 - 1 + row, colb = x0 - 2 + pp * 2;
            if ((unsigned)gy < (unsigned)H && (unsigned)colb < (unsigned)(W - 1)) {
                srcp[i] = (const char*)(inp + ((size_t)g * HW + (size_t)gy * W + colb) * 8);
                adv[i] = 4 * HW * 8;          // next phase: +4 planes
            }
        } else if (c < N_CHUNK) {
            int c2 = c - N_ACT_CH;            // 0..1151
            size_t o;
            if (c2 < 1024) {                  // MX: (t*2+q)*64+co64
                int gt = c2 >> 6, co = c2 & 63;
                o = ((size_t)gt * CO + co0 + co) * 16;
            } else {                          // tap8: q*64+co64
                int c3 = c2 - 1024;
                int q = c3 >> 6, co = c3 & 63;
                o = 256 * (size_t)CO + ((size_t)q * CO + co0 + co) * 16;
            }
            srcp[i] = (const char*)(wb + o);
            adv[i] = 288 * (size_t)CO;        // bytes per phase
        }
    }

    // per-lane phase-invariant read offsets
    int mxo[2];
    #pragma unroll
    for (int g = 0; g < 2; ++g) {
        int t = g * 4 + kq;
        int dy = t / 3, dx = t - dy * 3;
        mxo[g] = (dy * 20 + dx) * 8;
    }
    const int abase = ((wn * 4) * 20 + xl + 1) * 8;                  // + q*2880 + nt*160
    const int awmx  = WT_BOFF + kq * 2048 + xl * 16;                 // + g*8192 + q*1024 + mt*256
    const int aw8   = W8_BOFF + (kq >> 1) * 1024 + xl * 16 + (kq & 1) * 8;  // + mt*256
    const int ab8   = kq * 2880 + abase + (2 * 20 + 2) * 8;          // + nt*160

    const int P = CIN / 32;

    // prologue: stage phase 0 into buffer 0
    {
        char* d = smem + tid * 16;
        #pragma unroll
        for (int i = 0; i < 8; ++i) {
            gload_lds16(srcp[i], d + i * 4096);
            srcp[i] += adv[i];
        }
    }

    for (int p = 0; p < P; ++p) {
        __syncthreads();   // drains own loads (issued one compute-phase ago)

        if (p + 1 < P) {   // issue next phase into the other buffer
            char* d = smem + ((p + 1) & 1) * BUF_SZ + tid * 16;
            #pragma unroll
            for (int i = 0; i < 8; ++i) {
                gload_lds16(srcp[i], d + i * 4096);
                srcp[i] += adv[i];
            }
        }

        const char* base = smem + (p & 1) * BUF_SZ;

        // ---- 2 MX steps: taps 0-3, 4-7 (K = 4 taps x 32 ch = 128) ----
        #pragma unroll
        for (int g = 0; g < 2; ++g) {
            i32x8 A[4];
            #pragma unroll
            for (int mt = 0; mt < 4; ++mt) {
                const char* pa = base + awmx + g * 8192 + mt * 256;
                U2 u{*(const u32x4*)pa, *(const u32x4*)(pa + 1024)};
                A[mt] = __builtin_bit_cast(i32x8, u);
            }
            #pragma unroll
            for (int nt = 0; nt < 4; ++nt) {
                const char* pb = base + abase + mxo[g] + nt * 160;
                L4 l{*(const long*)pb, *(const long*)(pb + 2880),
                     *(const long*)(pb + 5760), *(const long*)(pb + 8640)};
                i32x8 B = __builtin_bit_cast(i32x8, l);
                #pragma unroll
                for (int mt = 0; mt < 4; ++mt)
                    acc[mt][nt] = __builtin_amdgcn_mfma_scale_f32_16x16x128_f8f6f4(
                        A[mt], B, acc[mt][nt], 0, 0,
                        0, 0x7F7F7F7F, 0, 0x7F7F7F7F);
            }
        }

        // ---- tap 8: plain fp8 K=32 step ----
        {
            long A8[4], B8[4];
            #pragma unroll
            for (int mt = 0; mt < 4; ++mt)
                A8[mt] = *(const long*)(base + aw8 + mt * 256);
            #pragma unroll
            for (int nt = 0; nt < 4; ++nt)
                B8[nt] = *(const long*)(base + ab8 + nt * 160);
            #pragma unroll
            for (int mt = 0; mt < 4; ++mt)
                #pragma unroll
                for (int nt = 0; nt < 4; ++nt)
                    acc[mt][nt] = __builtin_amdgcn_mfma_f32_16x16x32_fp8_fp8(
                        A8[mt], B8[nt], acc[mt][nt], 0, 0, 0);
        }
    }

    // ---- epilogue ----
    // C/D: col(px) = lane&15 = xl; row(co within 16) = kq*4 + reg.
    if (EPI == 0) {
        u8* out = (u8*)outv;
        #pragma unroll
        for (int nt = 0; nt < 4; ++nt) {
            const int y = y0 + wn * 4 + nt;
            #pragma unroll
            for (int mt = 0; mt < 4; ++mt) {
                const int cb = co0 + mt * 16 + kq * 4;
                const f32x4 bv = *(const f32x4*)(bias + cb);
                float v[4];
                #pragma unroll
                for (int r = 0; r < 4; ++r) v[r] = fmaxf(acc[mt][nt][r] + bv[r], 0.f);
                int w0 = __builtin_amdgcn_cvt_pk_fp8_f32(v[0], v[1], 0, false);
                w0 = __builtin_amdgcn_cvt_pk_fp8_f32(v[2], v[3], w0, true);
                *(int*)(out + (((size_t)img * (CO >> 3) + (cb >> 3)) * HW +
                               (size_t)y * W + x0 + xl) * 8 + (cb & 7)) = w0;
            }
        }
    } else if (EPI == 1) {
        u8* out = (u8*)outv;
        const int Hp = H >> 1, Wp = W >> 1;
        const size_t HWp = (size_t)Hp * Wp;
        #pragma unroll
        for (int j = 0; j < 2; ++j) {
            const int py = (y0 + wn * 4 + 2 * j) >> 1;
            const int px = (x0 + xl) >> 1;
            #pragma unroll
            for (int mt = 0; mt < 4; ++mt) {
                const int cb = co0 + mt * 16 + kq * 4;
                const f32x4 bv = *(const f32x4*)(bias + cb);
                float v[4];
                #pragma unroll
                for (int r = 0; r < 4; ++r) {
                    float a = acc[mt][2 * j][r] + bv[r];
                    float b = acc[mt][2 * j + 1][r] + bv[r];
                    float m = fmaxf(a, b);
                    m = fmaxf(m, __shfl_xor(m, 1));   // fold x pair
                    v[r] = fmaxf(m, 0.f);
                }
                if (!(lane & 1)) {
                    int w0 = __builtin_amdgcn_cvt_pk_fp8_f32(v[0], v[1], 0, false);
                    w0 = __builtin_amdgcn_cvt_pk_fp8_f32(v[2], v[3], w0, true);
                    *(int*)(out + (((size_t)img * (CO >> 3) + (cb >> 3)) * HWp +
                                   (size_t)py * Wp + px) * 8 + (cb & 7)) = w0;
                }
            }
        }
    } else if (EPI == 2) {
        bf16* out = (bf16*)outv;
        #pragma unroll
        for (int nt = 0; nt < 4; ++nt) {
            const int y = y0 + wn * 4 + nt;
            bf16* op = out + (((size_t)img * H + y) * W + (x0 + xl)) * CO;
            #pragma unroll
            for (int mt = 0; mt < 4; ++mt) {
                const int cb = co0 + mt * 16 + kq * 4;
                const f32x4 bv = *(const f32x4*)(bias + cb);
                us4 o;
                #pragma unroll
                for (int r = 0; r < 4; ++r)
                    o[r] = f2bf(fmaxf(acc[mt][nt][r] + bv[r], 0.f));
                *(us4*)(op + cb) = o;
            }
        }
    } else {
        float s = 0.f;
        #pragma unroll
        for (int nt = 0; nt < 4; ++nt) {
            const int y = y0 + wn * 4 + nt;
            const bf16* fp = fref + (((size_t)img * H + y) * W + (x0 + xl)) * CO;
            #pragma unroll
            for (int mt = 0; mt < 4; ++mt) {
                const int cb = co0 + mt * 16 + kq * 4;
                const f32x4 bv = *(const f32x4*)(bias + cb);
                us4 f = *(const us4*)(fp + cb);
                #pragma unroll
                for (int r = 0; r < 4; ++r) {
                    float v = fmaxf(acc[mt][nt][r] + bv[r], 0.f);
                    float d = bf2f(f2bf(v)) - bf2f(f[r]);
                    s += d * d;
                }
            }
        }
        // block reduce reusing smem (sync first: others may still read LDS)
        #pragma unroll
        for (int o = 32; o > 0; o >>= 1) s += __shfl_down(s, o, 64);
        __syncthreads();
        if (lane == 0) *(float*)(smem + wn * 4) = s;
        __syncthreads();
        if (tid == 0) {
            float tot = *(float*)(smem) + *(float*)(smem + 4) +
                        *(float*)(smem + 8) + *(float*)(smem + 12);
            atomicAdd(pacc, tot);
        }
    }
}

// ---------------------------------------------------------------------------
// launch
// ---------------------------------------------------------------------------
extern "C" void kernel_launch(void* const* d_in, const int* in_sizes, int n_in,
                              void* d_out, int out_size, void* d_ws, size_t ws_size,
                              hipStream_t stream) {
    const float* sr = (const float*)d_in[0];
    const float* hr = (const float*)d_in[1];
    const float* w1 = (const float*)d_in[2];
    const float* b1 = (const float*)d_in[3];
    const float* w2 = (const float*)d_in[4];
    const float* b2 = (const float*)d_in[5];
    const float* w3 = (const float*)d_in[6];
    const float* b3 = (const float*)d_in[7];
    const float* w4 = (const float*)d_in[8];
    const float* b4 = (const float*)d_in[9];
    float* out = (float*)d_out;

    char* ws = (char*)d_ws;
    size_t off = 0;
    float* accs = (float*)(ws + off); off += 256;
    float* zbuf = (float*)(ws + off); off += 256;
    u8* wb2 = (u8*)(ws + off); off += (size_t)128 * 9 * 64;
    u8* wb3 = (u8*)(ws + off); off += (size_t)256 * 9 * 128;
    u8* wb4 = (u8*)(ws + off); off += (size_t)256 * 9 * 256;
    const size_t fixed = (off + 255) & ~(size_t)255;

    const size_t MB = 1024u * 1024u;
    // per image: A 4MB (fp8 planar), P 2MB (fp8 planar), F 8MB (bf16) = 14MB
    int nb = 8;
    while (nb > 1 && fixed + (size_t)nb * 14 * MB > ws_size) nb >>= 1;

    u8*   A = (u8*)(ws + fixed);                          // fp8 planar
    u8*   P = (u8*)(ws + fixed + (size_t)nb * 4 * MB);    // fp8 planar pooled
    bf16* F = (bf16*)(ws + fixed + (size_t)nb * 6 * MB);  // bf16 NHWC

    zero_accs_kernel<<<1, 64, 0, stream>>>(accs, zbuf);
    wprep_mx_kernel<<<288, 256, 0, stream>>>(w2, wb2, 64, 128);
    wprep_mx_kernel<<<1152, 256, 0, stream>>>(w3, wb3, 128, 256);
    wprep_mx_kernel<<<2304, 256, 0, stream>>>(w4, wb4, 256, 256);
    mse_kernel<<<2048, 256, 0, stream>>>(sr, hr, accs + 0, 524288);
    ssim_kernel<<<dim3(245, 8), 256, 0, stream>>>(sr, hr, accs + 1);

    for (int b0 = 0; b0 < 8; b0 += nb) {
        // ---- sr pass: features -> F (bf16) ----
        conv1_kernel<<<dim3(256, nb), 256, 0, stream>>>(sr + (size_t)b0 * 65536, w1, b1, A);
        conv_mx<64, 1><<<dim3(16, 16, nb * 2), 256, 0, stream>>>(
            A, wb2, b2, P, 256, 256, 128, zbuf, nullptr, nullptr);
        conv_mx<128, 0><<<dim3(8, 8, nb * 4), 256, 0, stream>>>(
            P, wb3, b3, A, 128, 128, 256, zbuf, nullptr, nullptr);
        conv_mx<256, 2><<<dim3(8, 8, nb * 4), 256, 0, stream>>>(
            A, wb4, b4, F, 128, 128, 256, zbuf, nullptr, nullptr);
        // ---- hr pass: features, fused perceptual vs F ----
        conv1_kernel<<<dim3(256, nb), 256, 0, stream>>>(hr + (size_t)b0 * 65536, w1, b1, A);
        conv_mx<64, 1><<<dim3(16, 16, nb * 2), 256, 0, stream>>>(
            A, wb2, b2, P, 256, 256, 128, zbuf, nullptr, nullptr);
        conv_mx<128, 0><<<dim3(8, 8, nb * 4), 256, 0, stream>>>(
            P, wb3, b3, A, 128, 128, 256, zbuf, nullptr, nullptr);
        conv_mx<256, 3><<<dim3(8, 8, nb * 4), 256, 0, stream>>>(
            A, wb4, b4, nullptr, 128, 128, 256, zbuf, F, accs + 2);
    }

    finalize_kernel<<<1, 1, 0, stream>>>(accs, out);
}

// Round 12
// 448.282 us; speedup vs baseline: 3.4099x; 1.1163x over previous
//
#include <hip/hip_runtime.h>
#include <hip/hip_bf16.h>

typedef __hip_bfloat16 bf16;
typedef unsigned char u8;
typedef __attribute__((ext_vector_type(4))) float f32x4;
typedef __attribute__((ext_vector_type(2))) float f32x2;
typedef __attribute__((ext_vector_type(4))) unsigned short us4;
typedef __attribute__((ext_vector_type(8))) int i32x8;
typedef __attribute__((ext_vector_type(4))) unsigned int u32x4;

struct L4 { long a, b, c, d; };
struct U2 { u32x4 x, y; };

__device__ inline unsigned short f2bf(float f) {
    __hip_bfloat16 h = __float2bfloat16(f);
    return __builtin_bit_cast(unsigned short, h);
}

// async global->LDS 16B copy; LDS dst must be wave-uniform base + lane*16
typedef __attribute__((address_space(3))) unsigned int lds_uint;
typedef __attribute__((address_space(1))) const unsigned int g_uint;
__device__ inline void gload_lds16(const void* g, void* l) {
    __builtin_amdgcn_global_load_lds((g_uint*)g, (lds_uint*)l, 16, 0, 0);
}

__device__ inline void block_reduce_atomic(float v, float* dst) {
    #pragma unroll
    for (int o = 32; o > 0; o >>= 1) v += __shfl_down(v, o, 64);
    __shared__ float ws[8];
    const int lane = threadIdx.x & 63;
    const int wid  = threadIdx.x >> 6;
    if (lane == 0) ws[wid] = v;
    __syncthreads();
    if (threadIdx.x == 0) {
        float s = 0.f;
        const int nw = (blockDim.x + 63) >> 6;
        for (int i = 0; i < nw; ++i) s += ws[i];
        atomicAdd(dst, s);
    }
}

// ---------------------------------------------------------------------------
// prep: zero accumulators + repack all three conv weights to MX layout
// per 32ch phase p: [t(0..7)][q(16ch half)][CO][16B] then tap8 [q][CO][16B]
// ---------------------------------------------------------------------------
__global__ void prep_kernel(const float* __restrict__ w2, u8* __restrict__ wb2,
                            const float* __restrict__ w3, u8* __restrict__ wb3,
                            const float* __restrict__ w4, u8* __restrict__ wb4,
                            float* accs, float* zbuf) {
    int blk = blockIdx.x;
    if (blk == 0) {
        if (threadIdx.x < 8)  accs[threadIdx.x] = 0.f;
        if (threadIdx.x < 64) zbuf[threadIdx.x] = 0.f;
        return;
    }
    const float* w; u8* wb; int CIN, CO, idx;
    if (blk <= 288)       { w = w2; wb = wb2; CIN = 64;  CO = 128; idx = (blk - 1) * 256 + threadIdx.x; }
    else if (blk <= 1440) { w = w3; wb = wb3; CIN = 128; CO = 256; idx = (blk - 289) * 256 + threadIdx.x; }
    else                  { w = w4; wb = wb4; CIN = 256; CO = 256; idx = (blk - 1441) * 256 + threadIdx.x; }
    int n = CO * 9 * CIN;
    if (idx >= n) return;
    int t = idx % 9;
    int rest = idx / 9;
    int ci = rest % CIN;
    int co = rest / CIN;
    float v = w[idx];            // w flat = ((co*CIN+ci)*9 + t)
    int p = ci >> 5, c32 = ci & 31;
    size_t off = (size_t)p * 288 * CO;
    if (t < 8) {
        off += (((size_t)t * 2 + (c32 >> 4)) * CO + co) * 16 + (c32 & 15);
    } else {
        off += 256 * (size_t)CO + (((size_t)(c32 >> 4)) * CO + co) * 16 + (c32 & 15);
    }
    int r = __builtin_amdgcn_cvt_pk_fp8_f32(v, v, 0, false);
    wb[off] = (u8)(r & 0xff);
}

// ---------------------------------------------------------------------------
// loss: blocks [0,1960) = SSIM (b = blk/245), blocks [1960,2472) = MSE (f4)
// ---------------------------------------------------------------------------
__global__ void loss_kernel(const float* __restrict__ x, const float* __restrict__ y,
                            float* __restrict__ accs) {
    const int blk = blockIdx.x;
    float val = 0.f;
    float* dst;
    if (blk < 1960) {
        dst = accs + 1;
        const int b = blk / 245;
        const int t = (blk - b * 245) * 256 + threadIdx.x;
        if (t < 250 * 250) {
            const int i = t / 250, j = t - (t / 250) * 250;
            const float* xp = x + (size_t)b * 65536;
            const float* yp = y + (size_t)b * 65536;
            float sx = 0.f, sy = 0.f, sxx = 0.f, syy = 0.f, sxy = 0.f;
            #pragma unroll
            for (int dy = 0; dy < 7; ++dy) {
                const float* xr = xp + (size_t)(i + dy) * 256 + j;
                const float* yr = yp + (size_t)(i + dy) * 256 + j;
                #pragma unroll
                for (int dx = 0; dx < 7; ++dx) {
                    float a = xr[dx], c = yr[dx];
                    sx += a; sy += c;
                    sxx += a * a; syy += c * c; sxy += a * c;
                }
            }
            const float inv = 1.f / 49.f;
            const float cn  = 49.f / 48.f;
            float ux = sx * inv, uy = sy * inv;
            float vx  = cn * (sxx * inv - ux * ux);
            float vy  = cn * (syy * inv - uy * uy);
            float vxy = cn * (sxy * inv - ux * uy);
            const float C1 = 1e-4f, C2 = 9e-4f;
            val = ((2.f * ux * uy + C1) * (2.f * vxy + C2)) /
                  ((ux * ux + uy * uy + C1) * (vx + vy + C2));
        }
    } else {
        dst = accs + 0;
        int i = (blk - 1960) * 256 + threadIdx.x;   // < 131072 float4s
        float4 a = ((const float4*)x)[i];
        float4 b = ((const float4*)y)[i];
        float d0 = a.x - b.x, d1 = a.y - b.y, d2 = a.z - b.z, d3 = a.w - b.w;
        val = d0 * d0 + d1 * d1 + d2 * d2 + d3 * d3;
    }
    block_reduce_atomic(val, dst);
}

__global__ void finalize_kernel(const float* __restrict__ accs, float* __restrict__ out) {
    if (threadIdx.x == 0) {
        float mse    = accs[0] * (1.f / 524288.f);
        float ssim_l = 1.f - accs[1] * (1.f / 500000.f);
        float perc   = accs[2] * (1.f / 33554432.f);
        out[0] = mse + 0.5f * ssim_l + 0.1f * perc;
        out[1] = mse;
        out[2] = ssim_l;
        out[3] = perc;
    }
}

// ---------------------------------------------------------------------------
// conv1: CIN=1, CO=64, fp32 NCHW in -> fp8 planar NC8HW8 out, relu.
// img < nb -> sr image (b0+img); else hr image (b0+img-nb).
// ---------------------------------------------------------------------------
__global__ __launch_bounds__(256) void conv1_kernel(
    const float* __restrict__ sr, const float* __restrict__ hr, int nb, int b0,
    const float* __restrict__ w, const float* __restrict__ bias,
    u8* __restrict__ out) {
    const int H = 256, W = 256;
    const int img = blockIdx.y;
    const float* in = (img < nb) ? (sr + (size_t)(b0 + img) * 65536)
                                 : (hr + (size_t)(b0 + img - nb) * 65536);
    int px = blockIdx.x * 256 + threadIdx.x;
    int y = px >> 8, x = px & 255;
    float p[9];
    #pragma unroll
    for (int dy = 0; dy < 3; ++dy)
        #pragma unroll
        for (int dx = 0; dx < 3; ++dx) {
            int gy = y + dy - 1, gx = x + dx - 1;
            float v = 0.f;
            if ((unsigned)gy < (unsigned)H && (unsigned)gx < (unsigned)W)
                v = in[(size_t)gy * W + gx];
            p[dy * 3 + dx] = v;
        }
    #pragma unroll
    for (int g = 0; g < 8; ++g) {
        float v[8];
        #pragma unroll
        for (int c = 0; c < 8; ++c) {
            int co = g * 8 + c;
            float a = bias[co];
            #pragma unroll
            for (int k = 0; k < 9; ++k) a += w[co * 9 + k] * p[k];
            v[c] = fmaxf(a, 0.f);
        }
        uint2 o;
        int r;
        r = __builtin_amdgcn_cvt_pk_fp8_f32(v[0], v[1], 0, false);
        o.x = __builtin_amdgcn_cvt_pk_fp8_f32(v[2], v[3], r, true);
        r = __builtin_amdgcn_cvt_pk_fp8_f32(v[4], v[5], 0, false);
        o.y = __builtin_amdgcn_cvt_pk_fp8_f32(v[6], v[7], r, true);
        *(uint2*)(out + (((size_t)img * 8 + g) * 65536 + px) * 8) = o;
    }
}

// ---------------------------------------------------------------------------
// implicit-GEMM 3x3 SAME conv, planar-fp8 in -> planar-fp8 out.
// MX-scaled 16x16x128 f8f6f4 MFMA with TAP-PACKED K (4 taps x 32 ch per
// MFMA; lane's k-block = lane>>4 picks its tap, tap shift = per-lane LDS
// offset). Taps 0-3, 4-7 = two MX steps; tap 8 = plain fp8 16x16x32.
// Unit e8m0 scales (0x7F) => pure fp8 math at 2x rate.
// Block: 4 waves, tile = 64 co x (16y x 16x), wave m4n4; dbuf async staging
// (1872 chunks/phase, 2x32 KB LDS). All LDS reads conflict-free (planar).
// EPI: 0 = planar fp8 store, 1 = planar fp8 + fused 2x2 maxpool,
//      3 = fused perceptual sum((x - fref)^2) vs planar-fp8 fref, no store.
// ---------------------------------------------------------------------------
#define BUF_SZ   32768
#define N_ACT_CH 720
#define N_CHUNK  1872
#define WT_BOFF  11520     // 720*16

template <int CIN, int EPI>
__global__ __launch_bounds__(256, 2) void conv_mx(
    const u8* __restrict__ in,       // planar fp8
    const u8* __restrict__ wb,       // MX-packed weights (see prep)
    const float* __restrict__ bias,  // (CO)
    u8* __restrict__ out,
    int H, int W, int CO,
    const float* __restrict__ zbuf,  // zeroed scratch
    const u8* __restrict__ fref,     // EPI==3: reference features (planar fp8)
    float* __restrict__ pacc) {      // EPI==3: perceptual accumulator
    const int tid  = threadIdx.x;
    const int lane = tid & 63;
    const int wn   = tid >> 6;           // 4-row y strip
    const int xl = lane & 15;
    const int kq = lane >> 4;            // MX: tap-in-group; tap8: ch octet
    const int x0 = blockIdx.x * 16;
    const int y0 = blockIdx.y * 16;
    const int ngrp = CO >> 6;
    const int img = blockIdx.z / ngrp;
    const int co0 = (blockIdx.z - img * ngrp) << 6;

    __shared__ __align__(16) char smem[2 * BUF_SZ];

    f32x4 acc[4][4];
    #pragma unroll
    for (int m = 0; m < 4; ++m)
        #pragma unroll
        for (int n = 0; n < 4; ++n) acc[m][n] = (f32x4){0.f, 0.f, 0.f, 0.f};

    const size_t HW = (size_t)H * W;
    const u8* inp = in + (size_t)img * (CIN >> 3) * HW * 8;

    // ---- phase-invariant staging sources (chunk c = tid + i*256) ----
    const char* srcp[8];
    long adv[8];
    #pragma unroll
    for (int i = 0; i < 8; ++i) {
        int c = tid + i * 256;
        srcp[i] = (const char*)zbuf;
        adv[i] = 0;
        if (c < N_ACT_CH) {
            int g = c / 180, r = c - g * 180;
            int row = r / 10, pp = r - row * 10;
            int gy = y0 - 1 + row, colb = x0 - 2 + pp * 2;
            if ((unsigned)gy < (unsigned)H && (unsigned)colb < (unsigned)(W - 1)) {
                srcp[i] = (const char*)(inp + ((size_t)g * HW + (size_t)gy * W + colb) * 8);
                adv[i] = 4 * HW * 8;          // next phase: +4 planes
            }
        } else if (c < N_CHUNK) {
            int c2 = c - N_ACT_CH;            // 0..1151
            size_t o;
            if (c2 < 1024) {                  // MX: (t*2+q)*64+co64
                int gt = c2 >> 6, co = c2 & 63;
                o = ((size_t)gt * CO + co0 + co) * 16;
            } else {                          // tap8: q*64+co64
                int c3 = c2 - 1024;
                int q = c3 >> 6, co = c3 & 63;
                o = 256 * (size_t)CO + ((size_t)q * CO + co0 + co) * 16;
            }
            srcp[i] = (const char*)(wb + o);
            adv[i] = 288 * (size_t)CO;        // bytes per phase
        }
    }

    // per-lane phase-invariant read offsets
    int mxo[2];
    #pragma unroll
    for (int g = 0; g < 2; ++g) {
        int t = g * 4 + kq;
        int dy = t / 3, dx = t - dy * 3;
        mxo[g] = (dy * 20 + dx) * 8;
    }
    const int abase = ((wn * 4) * 20 + xl + 1) * 8;                  // + q*2880 + nt*160
    const int awmx  = WT_BOFF + kq * 2048 + xl * 16;                 // + g*8192 + q*1024 + mt*256
    const int aw8   = WT_BOFF + 16384 + (kq >> 1) * 1024 + xl * 16 + (kq & 1) * 8;  // + mt*256
    const int ab8   = kq * 2880 + abase + (2 * 20 + 2) * 8;          // + nt*160

    const int P = CIN / 32;

    // prologue: stage phase 0 into buffer 0
    {
        char* d = smem + tid * 16;
        #pragma unroll
        for (int i = 0; i < 8; ++i) {
            gload_lds16(srcp[i], d + i * 4096);
            srcp[i] += adv[i];
        }
    }

    for (int p = 0; p < P; ++p) {
        __syncthreads();   // drains own loads (issued one compute-phase ago)

        if (p + 1 < P) {   // issue next phase into the other buffer
            char* d = smem + ((p + 1) & 1) * BUF_SZ + tid * 16;
            #pragma unroll
            for (int i = 0; i < 8; ++i) {
                gload_lds16(srcp[i], d + i * 4096);
                srcp[i] += adv[i];
            }
        }

        const char* base = smem + (p & 1) * BUF_SZ;

        // ---- 2 MX steps: taps 0-3, 4-7 (K = 4 taps x 32 ch = 128) ----
        #pragma unroll
        for (int g = 0; g < 2; ++g) {
            i32x8 A[4];
            #pragma unroll
            for (int mt = 0; mt < 4; ++mt) {
                const char* pa = base + awmx + g * 8192 + mt * 256;
                U2 u{*(const u32x4*)pa, *(const u32x4*)(pa + 1024)};
                A[mt] = __builtin_bit_cast(i32x8, u);
            }
            #pragma unroll
            for (int nt = 0; nt < 4; ++nt) {
                const char* pb = base + abase + mxo[g] + nt * 160;
                L4 l{*(const long*)pb, *(const long*)(pb + 2880),
                     *(const long*)(pb + 5760), *(const long*)(pb + 8640)};
                i32x8 B = __builtin_bit_cast(i32x8, l);
                #pragma unroll
                for (int mt = 0; mt < 4; ++mt)
                    acc[mt][nt] = __builtin_amdgcn_mfma_scale_f32_16x16x128_f8f6f4(
                        A[mt], B, acc[mt][nt], 0, 0,
                        0, 0x7F7F7F7F, 0, 0x7F7F7F7F);
            }
        }

        // ---- tap 8: plain fp8 K=32 step ----
        {
            long A8[4], B8[4];
            #pragma unroll
            for (int mt = 0; mt < 4; ++mt)
                A8[mt] = *(const long*)(base + aw8 + mt * 256);
            #pragma unroll
            for (int nt = 0; nt < 4; ++nt)
                B8[nt] = *(const long*)(base + ab8 + nt * 160);
            #pragma unroll
            for (int mt = 0; mt < 4; ++mt)
                #pragma unroll
                for (int nt = 0; nt < 4; ++nt)
                    acc[mt][nt] = __builtin_amdgcn_mfma_f32_16x16x32_fp8_fp8(
                        A8[mt], B8[nt], acc[mt][nt], 0, 0, 0);
        }
    }

    // ---- epilogue ----
    // C/D: col(px) = lane&15 = xl; row(co within 16) = kq*4 + reg.
    if (EPI == 0) {
        #pragma unroll
        for (int nt = 0; nt < 4; ++nt) {
            const int y = y0 + wn * 4 + nt;
            #pragma unroll
            for (int mt = 0; mt < 4; ++mt) {
                const int cb = co0 + mt * 16 + kq * 4;
                const f32x4 bv = *(const f32x4*)(bias + cb);
                float v[4];
                #pragma unroll
                for (int r = 0; r < 4; ++r) v[r] = fmaxf(acc[mt][nt][r] + bv[r], 0.f);
                int w0 = __builtin_amdgcn_cvt_pk_fp8_f32(v[0], v[1], 0, false);
                w0 = __builtin_amdgcn_cvt_pk_fp8_f32(v[2], v[3], w0, true);
                *(int*)(out + (((size_t)img * (CO >> 3) + (cb >> 3)) * HW +
                               (size_t)y * W + x0 + xl) * 8 + (cb & 7)) = w0;
            }
        }
    } else if (EPI == 1) {
        const int Hp = H >> 1, Wp = W >> 1;
        const size_t HWp = (size_t)Hp * Wp;
        #pragma unroll
        for (int j = 0; j < 2; ++j) {
            const int py = (y0 + wn * 4 + 2 * j) >> 1;
            const int px = (x0 + xl) >> 1;
            #pragma unroll
            for (int mt = 0; mt < 4; ++mt) {
                const int cb = co0 + mt * 16 + kq * 4;
                const f32x4 bv = *(const f32x4*)(bias + cb);
                float v[4];
                #pragma unroll
                for (int r = 0; r < 4; ++r) {
                    float a = acc[mt][2 * j][r] + bv[r];
                    float b = acc[mt][2 * j + 1][r] + bv[r];
                    float m = fmaxf(a, b);
                    m = fmaxf(m, __shfl_xor(m, 1));   // fold x pair
                    v[r] = fmaxf(m, 0.f);
                }
                if (!(lane & 1)) {
                    int w0 = __builtin_amdgcn_cvt_pk_fp8_f32(v[0], v[1], 0, false);
                    w0 = __builtin_amdgcn_cvt_pk_fp8_f32(v[2], v[3], w0, true);
                    *(int*)(out + (((size_t)img * (CO >> 3) + (cb >> 3)) * HWp +
                                   (size_t)py * Wp + px) * 8 + (cb & 7)) = w0;
                }
            }
        }
    } else {
        float s = 0.f;
        #pragma unroll
        for (int nt = 0; nt < 4; ++nt) {
            const int y = y0 + wn * 4 + nt;
            #pragma unroll
            for (int mt = 0; mt < 4; ++mt) {
                const int cb = co0 + mt * 16 + kq * 4;
                const f32x4 bv = *(const f32x4*)(bias + cb);
                int f = *(const int*)(fref + (((size_t)img * (CO >> 3) + (cb >> 3)) * HW +
                                              (size_t)y * W + x0 + xl) * 8 + (cb & 7));
                f32x2 flo = __builtin_amdgcn_cvt_pk_f32_fp8(f, false);  // ch r=0,1
                f32x2 fhi = __builtin_amdgcn_cvt_pk_f32_fp8(f, true);   // ch r=2,3
                float fr[4] = {flo[0], flo[1], fhi[0], fhi[1]};
                #pragma unroll
                for (int r = 0; r < 4; ++r) {
                    float v = fmaxf(acc[mt][nt][r] + bv[r], 0.f);
                    float d = fr[r] - v;
                    s += d * d;
                }
            }
        }
        // block reduce reusing smem (sync first: others may still read LDS)
        #pragma unroll
        for (int o = 32; o > 0; o >>= 1) s += __shfl_down(s, o, 64);
        __syncthreads();
        if (lane == 0) *(float*)(smem + wn * 4) = s;
        __syncthreads();
        if (tid == 0) {
            float tot = *(float*)(smem) + *(float*)(smem + 4) +
                        *(float*)(smem + 8) + *(float*)(smem + 12);
            atomicAdd(pacc, tot);
        }
    }
}

// ---------------------------------------------------------------------------
// launch
// ---------------------------------------------------------------------------
extern "C" void kernel_launch(void* const* d_in, const int* in_sizes, int n_in,
                              void* d_out, int out_size, void* d_ws, size_t ws_size,
                              hipStream_t stream) {
    const float* sr = (const float*)d_in[0];
    const float* hr = (const float*)d_in[1];
    const float* w1 = (const float*)d_in[2];
    const float* b1 = (const float*)d_in[3];
    const float* w2 = (const float*)d_in[4];
    const float* b2 = (const float*)d_in[5];
    const float* w3 = (const float*)d_in[6];
    const float* b3 = (const float*)d_in[7];
    const float* w4 = (const float*)d_in[8];
    const float* b4 = (const float*)d_in[9];
    float* out = (float*)d_out;

    char* ws = (char*)d_ws;
    size_t off = 0;
    float* accs = (float*)(ws + off); off += 256;
    float* zbuf = (float*)(ws + off); off += 256;
    u8* wb2 = (u8*)(ws + off); off += (size_t)128 * 9 * 64;
    u8* wb3 = (u8*)(ws + off); off += (size_t)256 * 9 * 128;
    u8* wb4 = (u8*)(ws + off); off += (size_t)256 * 9 * 256;
    const size_t fixed = (off + 255) & ~(size_t)255;

    const size_t MB = 1024u * 1024u;
    // per batch-image pair (sr+hr): A 8MB, P 4MB, F 2MB = 14MB
    int nb = 8;
    while (nb > 1 && fixed + (size_t)nb * 14 * MB > ws_size) nb >>= 1;

    u8* A = (u8*)(ws + fixed);                          // (2nb,...) fp8 planar (conv1 out / conv3 out)
    u8* P = (u8*)(ws + fixed + (size_t)nb * 8 * MB);    // (2nb,128,128,128) fp8 planar pooled
    u8* F = (u8*)(ws + fixed + (size_t)nb * 12 * MB);   // (nb,128,128,256) fp8 planar (sr features)

    prep_kernel<<<3745, 256, 0, stream>>>(w2, wb2, w3, wb3, w4, wb4, accs, zbuf);
    loss_kernel<<<2472, 256, 0, stream>>>(sr, hr, accs);

    for (int b0 = 0; b0 < 8; b0 += nb) {
        const int ni = 2 * nb;   // sr images then hr images
        // conv1 (sr+hr merged) -> A
        conv1_kernel<<<dim3(256, ni), 256, 0, stream>>>(sr, hr, nb, b0, w1, b1, A);
        // conv2 + fused pool (merged) -> P
        conv_mx<64, 1><<<dim3(16, 16, ni * 2), 256, 0, stream>>>(
            A, wb2, b2, P, 256, 256, 128, zbuf, nullptr, nullptr);
        // conv3 (merged) -> A (reuse)
        conv_mx<128, 0><<<dim3(8, 8, ni * 4), 256, 0, stream>>>(
            P, wb3, b3, A, 128, 128, 256, zbuf, nullptr, nullptr);
        // conv4 sr (imgs 0..nb-1) -> F (planar fp8)
        conv_mx<256, 0><<<dim3(8, 8, nb * 4), 256, 0, stream>>>(
            A, wb4, b4, F, 128, 128, 256, zbuf, nullptr, nullptr);
        // conv4 hr (imgs nb..2nb-1), fused perceptual vs F
        conv_mx<256, 3><<<dim3(8, 8, nb * 4), 256, 0, stream>>>(
            A + (size_t)nb * 4 * MB, wb4, b4, nullptr, 128, 128, 256, zbuf, F, accs + 2);
    }

    finalize_kernel<<<1, 1, 0, stream>>>(accs, out);
}